// Round 3
// baseline (331.578 us; speedup 1.0000x reference)
//
#include <hip/hip_runtime.h>
#include <math.h>

#define SEQ 4096
#define DIM 1024
#define HEADS 8
#define DINNER 512
#define QKVW 1536
#define PAD 80   // LDS row stride in bf16 elems: 160B = 10 x 16B granules, balanced banks
#define CHUNK 8  // K-tiles (of 64) per split-KV chunk; 2304 real blocks -> sustained occupancy

typedef unsigned short u16;
typedef __attribute__((ext_vector_type(8))) short s8v;   // 8 bf16 (4 VGPRs)
typedef __attribute__((ext_vector_type(4))) float f4v;   // 4 fp32 acc
#define MFMA(a, b, c) __builtin_amdgcn_mfma_f32_16x16x32_bf16(a, b, c, 0, 0, 0)

__device__ __forceinline__ u16 f2bf(float f) {
    unsigned u = __float_as_uint(f);
    u += 0x7fff + ((u >> 16) & 1);   // RNE
    return (u16)(u >> 16);
}
__device__ __forceinline__ float bf2f(u16 b) { return __uint_as_float(((unsigned)b) << 16); }

// chunk-tile flat index: T = h*288 + base8(qt) + c, base8 = sum_{j=1..qt} ceil(j/8)
__device__ __forceinline__ int base8(int qt) {
    int tq = qt >> 3, rr = qt & 7;
    return 4 * tq * (tq + 1) + rr * (tq + 1);
}
// partials live in d_out (tiles 0..1023), dead wqt region (1024..1407), ws (1408..2303)
__device__ __forceinline__ float* po_sel(int T, float* pd, float* pw, float* ps) {
    if (T < 1024) return pd + (size_t)T * 4096;
    if (T < 1408) return pw + (size_t)(T - 1024) * 4096;
    return ps + (size_t)(T - 1408) * 4096;
}

// ---------- RMSNorm -> split bf16 (hi, lo) ----------
__global__ __launch_bounds__(256) void rmsnorm_split(const float* __restrict__ x,
                                                     const float* __restrict__ gamma,
                                                     u16* __restrict__ hi,
                                                     u16* __restrict__ lo) {
    __shared__ float red[4];
    const int row = blockIdx.x, t = threadIdx.x;
    const float* xr = x + (size_t)row * DIM;
    float v[4];
    float ss = 0.f;
#pragma unroll
    for (int i = 0; i < 4; ++i) { v[i] = xr[t + i * 256]; ss += v[i] * v[i]; }
#pragma unroll
    for (int off = 32; off >= 1; off >>= 1) ss += __shfl_xor(ss, off, 64);
    if ((t & 63) == 0) red[t >> 6] = ss;
    __syncthreads();
    float scale = 32.0f / fmaxf(sqrtf(red[0] + red[1] + red[2] + red[3]), 1e-12f);
#pragma unroll
    for (int i = 0; i < 4; ++i) {
        int c = t + i * 256;
        float y = v[i] * scale * gamma[c];
        u16 h = f2bf(y);
        hi[(size_t)row * DIM + c] = h;
        lo[(size_t)row * DIM + c] = f2bf(y - bf2f(h));
    }
}

// ---------- transpose fp32 [R][C] -> bf16 hi/lo [C][R] ----------
__global__ __launch_bounds__(256) void transpose_split(const float* __restrict__ in,
                                                       u16* __restrict__ hi,
                                                       u16* __restrict__ lo,
                                                       int R, int C, int want_lo) {
    __shared__ float tile[64][65];
    const int c0 = blockIdx.x * 64, r0 = blockIdx.y * 64;
    const int t = threadIdx.x, col = t & 63, rb = t >> 6;
#pragma unroll
    for (int j = 0; j < 16; ++j)
        tile[rb + j * 4][col] = in[(size_t)(r0 + rb + j * 4) * C + c0 + col];
    __syncthreads();
#pragma unroll
    for (int j = 0; j < 16; ++j) {
        int cc = rb + j * 4;
        float v = tile[col][cc];
        size_t oi = (size_t)(c0 + cc) * R + r0 + col;
        u16 h = f2bf(v);
        hi[oi] = h;
        if (want_lo) lo[oi] = f2bf(v - bf2f(h));
    }
}

// ---------- QKV GEMM, split-bf16 (3 MFMAs), fused split/scale epilogue ----------
__global__ __launch_bounds__(256) void gemm_qkv_split(
    const u16* __restrict__ Ah, const u16* __restrict__ Al,
    const u16* __restrict__ Bh, const u16* __restrict__ Bl,
    u16* __restrict__ qh, u16* __restrict__ ql,
    u16* __restrict__ kh, u16* __restrict__ kl, u16* __restrict__ vtp) {
    __shared__ u16 Ash[64 * PAD], Asl[64 * PAD], Bsh[64 * PAD], Bsl[64 * PAD];
    const int t = threadIdx.x;
    const int bn = blockIdx.x * 64, bm = blockIdx.y * 64;
    const int w = t >> 6, lane = t & 63, m = lane & 15, q = lane >> 4;
    f4v acc[4] = {{0.f, 0.f, 0.f, 0.f}, {0.f, 0.f, 0.f, 0.f},
                  {0.f, 0.f, 0.f, 0.f}, {0.f, 0.f, 0.f, 0.f}};
    for (int k0 = 0; k0 < DIM; k0 += 64) {
        __syncthreads();
#pragma unroll
        for (int i = 0; i < 2; ++i) {
            int c = t + i * 256, row = c >> 3, ch = (c & 7) * 8;
            *(uint4*)&Ash[row * PAD + ch] = *(const uint4*)&Ah[(size_t)(bm + row) * DIM + k0 + ch];
            *(uint4*)&Asl[row * PAD + ch] = *(const uint4*)&Al[(size_t)(bm + row) * DIM + k0 + ch];
            *(uint4*)&Bsh[row * PAD + ch] = *(const uint4*)&Bh[(size_t)(bn + row) * DIM + k0 + ch];
            *(uint4*)&Bsl[row * PAD + ch] = *(const uint4*)&Bl[(size_t)(bn + row) * DIM + k0 + ch];
        }
        __syncthreads();
#pragma unroll
        for (int kk = 0; kk < 64; kk += 32) {
            s8v ah = *(const s8v*)&Ash[(w * 16 + m) * PAD + kk + q * 8];
            s8v al = *(const s8v*)&Asl[(w * 16 + m) * PAD + kk + q * 8];
#pragma unroll
            for (int ct = 0; ct < 4; ++ct) {
                s8v bh = *(const s8v*)&Bsh[(ct * 16 + m) * PAD + kk + q * 8];
                s8v bl = *(const s8v*)&Bsl[(ct * 16 + m) * PAD + kk + q * 8];
                acc[ct] = MFMA(ah, bh, acc[ct]);
                acc[ct] = MFMA(al, bh, acc[ct]);
                acc[ct] = MFMA(ah, bl, acc[ct]);
            }
        }
    }
    const int region = bn >> 9;   // uniform per block
#pragma unroll
    for (int ct = 0; ct < 4; ++ct) {
#pragma unroll
        for (int r = 0; r < 4; ++r) {
            int gr = bm + w * 16 + q * 4 + r;
            int gc = bn + ct * 16 + m;
            float v = acc[ct][r];
            if (region == 0) {
                v *= 8.0f;   // q * sqrt(d), faithful to reference
                u16 h = f2bf(v);
                qh[(size_t)gr * DINNER + gc] = h;
                ql[(size_t)gr * DINNER + gc] = f2bf(v - bf2f(h));
            } else if (region == 1) {
                u16 h = f2bf(v);
                kh[(size_t)gr * DINNER + (gc - 512)] = h;
                kl[(size_t)gr * DINNER + (gc - 512)] = f2bf(v - bf2f(h));
            } else {
                vtp[(size_t)(gc - 1024) * SEQ + gr] = f2bf(v);
            }
        }
    }
}

// ---------- split-KV flash attention chunk kernel, swapped QK^T ----------
// S^T = MFMA(K_frag, Q_frag): same LDS addresses / register fragments as before, operands
// swapped. Lane (m, g=lane>>4) holds S[q = w*16+m][kv = ct*16 + g*4 + r] -> softmax row
// stats are lane-local (15 fmax in-reg) + 2 shuffles (xor 16, 32) instead of 32 shuffles.
// P is written back transposed-to-row-major as 4 packed ds_write_b64 (was 16 b16 writes).
// alpha/inv live at lanes m==q_local; redistributed to the o-layout (row g*4+r) via bpermute.
__global__ __launch_bounds__(256) void attn_chunk(
    const u16* __restrict__ qhp, const u16* __restrict__ qlp,
    const u16* __restrict__ kh, const u16* __restrict__ kl,
    const u16* __restrict__ vt,
    float* __restrict__ po_dout, float* __restrict__ po_wqt,
    float* __restrict__ po_ws, float* __restrict__ ml) {
    __shared__ u16 KP[64 * PAD], Kl[64 * PAD], Vt[64 * PAD];
    const int t = threadIdx.x;
    const int bx = blockIdx.x;
    const int qt = 63 - (bx >> 3), c = bx & 7, h = blockIdx.y;
    if (c * CHUNK > qt) return;
    const int kt0 = c * CHUNK;
    const int kt1 = (qt < kt0 + CHUNK - 1) ? qt : (kt0 + CHUNK - 1);
    const int w = t >> 6, lane = t & 63, m = lane & 15, g = lane >> 4;

    // Q fragments in registers: row = qt*64 + w*16 + m, d-cols g*8 (+0 / +32)
    const size_t qrow = (size_t)(qt * 64 + w * 16 + m) * DINNER + h * 64;
    const s8v qf_h0 = *(const s8v*)&qhp[qrow + g * 8];
    const s8v qf_h1 = *(const s8v*)&qhp[qrow + 32 + g * 8];
    const s8v qf_l0 = *(const s8v*)&qlp[qrow + g * 8];
    const s8v qf_l1 = *(const s8v*)&qlp[qrow + 32 + g * 8];

    f4v o[4] = {{0.f, 0.f, 0.f, 0.f}, {0.f, 0.f, 0.f, 0.f},
                {0.f, 0.f, 0.f, 0.f}, {0.f, 0.f, 0.f, 0.f}};
    float mi_s = -1e30f, li_s = 0.f;   // per-lane stats for q = w*16 + m (4 copies over g)

    for (int kt = kt0; kt <= kt1; ++kt) {
        __syncthreads();   // prior iteration's P/Vt consumers done
#pragma unroll
        for (int i = 0; i < 2; ++i) {
            int c2 = t + i * 256, row = c2 >> 3, ch = (c2 & 7) * 8;
            *(uint4*)&KP[row * PAD + ch] =
                *(const uint4*)&kh[(size_t)(kt * 64 + row) * DINNER + h * 64 + ch];
            *(uint4*)&Kl[row * PAD + ch] =
                *(const uint4*)&kl[(size_t)(kt * 64 + row) * DINNER + h * 64 + ch];
            *(uint4*)&Vt[row * PAD + ch] =
                *(const uint4*)&vt[(size_t)(h * 64 + row) * SEQ + kt * 64 + ch];
        }
        __syncthreads();

        // S^T: s[ct][r] = S[q=w*16+m][kv=ct*16+g*4+r]; 3 MFMAs per 16x16x32 (split bf16)
        f4v s[4] = {{0.f, 0.f, 0.f, 0.f}, {0.f, 0.f, 0.f, 0.f},
                    {0.f, 0.f, 0.f, 0.f}, {0.f, 0.f, 0.f, 0.f}};
#pragma unroll
        for (int ct = 0; ct < 4; ++ct) {
            s8v bh0 = *(const s8v*)&KP[(ct * 16 + m) * PAD + g * 8];
            s8v bl0 = *(const s8v*)&Kl[(ct * 16 + m) * PAD + g * 8];
            s[ct] = MFMA(bh0, qf_h0, s[ct]);
            s[ct] = MFMA(bh0, qf_l0, s[ct]);
            s[ct] = MFMA(bl0, qf_h0, s[ct]);
            s8v bh1 = *(const s8v*)&KP[(ct * 16 + m) * PAD + 32 + g * 8];
            s8v bl1 = *(const s8v*)&Kl[(ct * 16 + m) * PAD + 32 + g * 8];
            s[ct] = MFMA(bh1, qf_h1, s[ct]);
            s[ct] = MFMA(bh1, qf_l1, s[ct]);
            s[ct] = MFMA(bl1, qf_h1, s[ct]);
        }
        if (kt == qt) {   // causal: mask kv > q (tile-local)
#pragma unroll
            for (int ct = 0; ct < 4; ++ct)
#pragma unroll
                for (int r = 0; r < 4; ++r)
                    if (ct * 16 + g * 4 + r > w * 16 + m) s[ct][r] = -1e30f;
        }

        // lane-local online softmax for q = w*16+m (16 kv values per lane)
        float rm = -1e30f;
#pragma unroll
        for (int ct = 0; ct < 4; ++ct)
#pragma unroll
            for (int r = 0; r < 4; ++r) rm = fmaxf(rm, s[ct][r]);
        rm = fmaxf(rm, __shfl_xor(rm, 16, 64));
        rm = fmaxf(rm, __shfl_xor(rm, 32, 64));
        float mn = fmaxf(mi_s, rm);
        float al = __expf(mi_s - mn);
        mi_s = mn;
        float rs = 0.f;
#pragma unroll
        for (int ct = 0; ct < 4; ++ct)
#pragma unroll
            for (int r = 0; r < 4; ++r) {
                s[ct][r] = __expf(s[ct][r] - mn);
                rs += s[ct][r];
            }
        rs += __shfl_xor(rs, 16, 64);
        rs += __shfl_xor(rs, 32, 64);
        li_s = li_s * al + rs;
        // alpha for o rows (q_local = g*4+r) lives at lane m == q_local
        float alo[4];
#pragma unroll
        for (int r = 0; r < 4; ++r) alo[r] = __shfl(al, g * 4 + r, 64);

        __syncthreads();   // all waves done reading KP as K-hi before P overwrite
#pragma unroll
        for (int ct = 0; ct < 4; ++ct) {
            unsigned w0 = (unsigned)f2bf(s[ct][0]) | ((unsigned)f2bf(s[ct][1]) << 16);
            unsigned w1 = (unsigned)f2bf(s[ct][2]) | ((unsigned)f2bf(s[ct][3]) << 16);
            *(uint2*)&KP[(w * 16 + m) * PAD + ct * 16 + g * 4] = make_uint2(w0, w1);
        }
#pragma unroll
        for (int ct = 0; ct < 4; ++ct)
#pragma unroll
            for (int r = 0; r < 4; ++r) o[ct][r] *= alo[r];
        // PV: each wave reads only its own P rows (w*16..w*16+15) -> no barrier needed
#pragma unroll
        for (int kk = 0; kk < 64; kk += 32) {
            s8v ap = *(const s8v*)&KP[(w * 16 + m) * PAD + kk + g * 8];
#pragma unroll
            for (int ct = 0; ct < 4; ++ct) {
                s8v bv = *(const s8v*)&Vt[(ct * 16 + m) * PAD + kk + g * 8];
                o[ct] = MFMA(ap, bv, o[ct]);
            }
        }
    }

    // epilogue: raw partial o (fp32) + per-row (m, l)
    const int T = h * 288 + base8(qt) + c;
    float* po = po_sel(T, po_dout, po_wqt, po_ws);
#pragma unroll
    for (int ct = 0; ct < 4; ++ct)
#pragma unroll
        for (int r = 0; r < 4; ++r)
            po[(size_t)(w * 16 + g * 4 + r) * 64 + ct * 16 + m] = o[ct][r];
    if (g == 0) {
        ml[(size_t)T * 128 + w * 16 + m] = mi_s;
        ml[(size_t)T * 128 + 64 + w * 16 + m] = li_s;
    }
}

// ---------- merge split-KV partials -> atto bf16 ----------
__global__ __launch_bounds__(256) void attn_merge(
    float* __restrict__ po_dout, float* __restrict__ po_wqt,
    float* __restrict__ po_ws, const float* __restrict__ ml,
    u16* __restrict__ atto) {
    const int qt = blockIdx.x, h = blockIdx.y;
    const int nc = (qt >> 3) + 1;
    const int t = threadIdx.x, col = t & 63, rg = t >> 6;
    const int T0 = h * 288 + base8(qt);
    for (int j = 0; j < 16; ++j) {
        int row = rg * 16 + j;
        float mv[8], lv[8], M = -1e30f;
#pragma unroll 8
        for (int cc = 0; cc < 8; ++cc)
            if (cc < nc) {
                mv[cc] = ml[(size_t)(T0 + cc) * 128 + row];
                lv[cc] = ml[(size_t)(T0 + cc) * 128 + 64 + row];
                M = fmaxf(M, mv[cc]);
            }
        float acc = 0.f, den = 0.f;
#pragma unroll 8
        for (int cc = 0; cc < 8; ++cc)
            if (cc < nc) {
                const float* po = po_sel(T0 + cc, po_dout, po_wqt, po_ws);
                float wg = __expf(mv[cc] - M);
                den += lv[cc] * wg;
                acc += wg * po[(size_t)row * 64 + col];
            }
        atto[(size_t)(qt * 64 + row) * DINNER + h * 64 + col] = f2bf(acc / den);
    }
}

// ---------- fallback: original fused flash attention (used if workspace too small) ----------
__global__ __launch_bounds__(256) void attn_mfma(
    const u16* __restrict__ qh, const u16* __restrict__ ql,
    const u16* __restrict__ kh, const u16* __restrict__ kl,
    const u16* __restrict__ vt, u16* __restrict__ atto) {
    __shared__ u16 Qh[64 * PAD], Ql[64 * PAD], KP[64 * PAD], Kl[64 * PAD], Vt[64 * PAD];
    const int t = threadIdx.x;
    const int qt = blockIdx.x, h = blockIdx.y;
    const int w = t >> 6, lane = t & 63, m = lane & 15, q = lane >> 4;

#pragma unroll
    for (int i = 0; i < 2; ++i) {
        int c = t + i * 256, row = c >> 3, ch = (c & 7) * 8;
        *(uint4*)&Qh[row * PAD + ch] =
            *(const uint4*)&qh[(size_t)(qt * 64 + row) * DINNER + h * 64 + ch];
        *(uint4*)&Ql[row * PAD + ch] =
            *(const uint4*)&ql[(size_t)(qt * 64 + row) * DINNER + h * 64 + ch];
    }

    f4v o[4] = {{0.f, 0.f, 0.f, 0.f}, {0.f, 0.f, 0.f, 0.f},
                {0.f, 0.f, 0.f, 0.f}, {0.f, 0.f, 0.f, 0.f}};
    float mi[4] = {-1e30f, -1e30f, -1e30f, -1e30f};
    float li[4] = {0.f, 0.f, 0.f, 0.f};

    for (int kt = 0; kt <= qt; ++kt) {
        __syncthreads();
#pragma unroll
        for (int i = 0; i < 2; ++i) {
            int c = t + i * 256, row = c >> 3, ch = (c & 7) * 8;
            *(uint4*)&KP[row * PAD + ch] =
                *(const uint4*)&kh[(size_t)(kt * 64 + row) * DINNER + h * 64 + ch];
            *(uint4*)&Kl[row * PAD + ch] =
                *(const uint4*)&kl[(size_t)(kt * 64 + row) * DINNER + h * 64 + ch];
            *(uint4*)&Vt[row * PAD + ch] =
                *(const uint4*)&vt[(size_t)(h * 64 + row) * SEQ + kt * 64 + ch];
        }
        __syncthreads();

        f4v s[4] = {{0.f, 0.f, 0.f, 0.f}, {0.f, 0.f, 0.f, 0.f},
                    {0.f, 0.f, 0.f, 0.f}, {0.f, 0.f, 0.f, 0.f}};
#pragma unroll
        for (int kk = 0; kk < 64; kk += 32) {
            s8v ah = *(const s8v*)&Qh[(w * 16 + m) * PAD + kk + q * 8];
            s8v al = *(const s8v*)&Ql[(w * 16 + m) * PAD + kk + q * 8];
#pragma unroll
            for (int ct = 0; ct < 4; ++ct) {
                s8v bh = *(const s8v*)&KP[(ct * 16 + m) * PAD + kk + q * 8];
                s8v bl = *(const s8v*)&Kl[(ct * 16 + m) * PAD + kk + q * 8];
                s[ct] = MFMA(ah, bh, s[ct]);
                s[ct] = MFMA(al, bh, s[ct]);
                s[ct] = MFMA(ah, bl, s[ct]);
            }
        }
        if (kt == qt) {
#pragma unroll
            for (int ct = 0; ct < 4; ++ct)
#pragma unroll
                for (int r = 0; r < 4; ++r)
                    if (ct * 16 + m > w * 16 + q * 4 + r) s[ct][r] = -1e30f;
        }

        float alpha[4];
#pragma unroll
        for (int r = 0; r < 4; ++r) {
            float rm = fmaxf(fmaxf(s[0][r], s[1][r]), fmaxf(s[2][r], s[3][r]));
#pragma unroll
            for (int off = 8; off >= 1; off >>= 1) rm = fmaxf(rm, __shfl_xor(rm, off, 64));
            float mn = fmaxf(mi[r], rm);
            alpha[r] = __expf(mi[r] - mn);
            mi[r] = mn;
            float rs = 0.f;
#pragma unroll
            for (int ct = 0; ct < 4; ++ct) {
                s[ct][r] = __expf(s[ct][r] - mn);
                rs += s[ct][r];
            }
#pragma unroll
            for (int off = 8; off >= 1; off >>= 1) rs += __shfl_xor(rs, off, 64);
            li[r] = li[r] * alpha[r] + rs;
        }

        __syncthreads();
#pragma unroll
        for (int ct = 0; ct < 4; ++ct)
#pragma unroll
            for (int r = 0; r < 4; ++r) {
                KP[(w * 16 + q * 4 + r) * PAD + ct * 16 + m] = f2bf(s[ct][r]);
                o[ct][r] *= alpha[r];
            }
#pragma unroll
        for (int kk = 0; kk < 64; kk += 32) {
            s8v ap = *(const s8v*)&KP[(w * 16 + m) * PAD + kk + q * 8];
#pragma unroll
            for (int ct = 0; ct < 4; ++ct) {
                s8v bv = *(const s8v*)&Vt[(ct * 16 + m) * PAD + kk + q * 8];
                o[ct] = MFMA(ap, bv, o[ct]);
            }
        }
    }

#pragma unroll
    for (int r = 0; r < 4; ++r) {
        float inv = 1.0f / li[r];
#pragma unroll
        for (int ct = 0; ct < 4; ++ct)
            atto[(size_t)(qt * 64 + w * 16 + q * 4 + r) * DINNER + h * 64 + ct * 16 + m] =
                f2bf(o[ct][r] * inv);
    }
}

// ---------- out projection: atto bf16 [4096][512] @ w_out^T bf16 [1024][512] -> fp32 ----------
__global__ __launch_bounds__(256) void gemm_out_bf16(const u16* __restrict__ A,
                                                     const u16* __restrict__ Bt,
                                                     float* __restrict__ C) {
    __shared__ u16 As[64 * PAD], Bs[64 * PAD];
    const int t = threadIdx.x;
    const int bn = blockIdx.x * 64, bm = blockIdx.y * 64;
    const int w = t >> 6, lane = t & 63, m = lane & 15, q = lane >> 4;
    f4v acc[4] = {{0.f, 0.f, 0.f, 0.f}, {0.f, 0.f, 0.f, 0.f},
                  {0.f, 0.f, 0.f, 0.f}, {0.f, 0.f, 0.f, 0.f}};
    for (int k0 = 0; k0 < DINNER; k0 += 64) {
        __syncthreads();
#pragma unroll
        for (int i = 0; i < 2; ++i) {
            int c = t + i * 256, row = c >> 3, ch = (c & 7) * 8;
            *(uint4*)&As[row * PAD + ch] = *(const uint4*)&A[(size_t)(bm + row) * DINNER + k0 + ch];
            *(uint4*)&Bs[row * PAD + ch] = *(const uint4*)&Bt[(size_t)(bn + row) * DINNER + k0 + ch];
        }
        __syncthreads();
#pragma unroll
        for (int kk = 0; kk < 64; kk += 32) {
            s8v a = *(const s8v*)&As[(w * 16 + m) * PAD + kk + q * 8];
#pragma unroll
            for (int ct = 0; ct < 4; ++ct) {
                s8v b = *(const s8v*)&Bs[(ct * 16 + m) * PAD + kk + q * 8];
                acc[ct] = MFMA(a, b, acc[ct]);
            }
        }
    }
#pragma unroll
    for (int ct = 0; ct < 4; ++ct)
#pragma unroll
        for (int r = 0; r < 4; ++r)
            C[(size_t)(bm + w * 16 + q * 4 + r) * DIM + bn + ct * 16 + m] = acc[ct][r];
}

extern "C" void kernel_launch(void* const* d_in, const int* in_sizes, int n_in,
                              void* d_out, int out_size, void* d_ws, size_t ws_size,
                              hipStream_t stream) {
    const float* x     = (const float*)d_in[0];
    const float* gamma = (const float*)d_in[1];
    const float* w_qkv = (const float*)d_in[2];
    const float* w_out = (const float*)d_in[3];
    float* out = (float*)d_out;

    // normed hi/lo live in d_out (2 * 4096*1024 * 2B == 4096*1024 * 4B, exact fit;
    // fully consumed by gemm_qkv before attention partials overwrite d_out)
    u16* nh = (u16*)d_out;
    u16* nl = nh + (size_t)SEQ * DIM;

    u16* p = (u16*)d_ws;
    u16* wqt_h = p; p += (size_t)QKVW * DIM;
    u16* wqt_l = p; p += (size_t)QKVW * DIM;
    u16* wot   = p; p += (size_t)DIM * DINNER;
    u16* qh = p; p += (size_t)SEQ * DINNER;
    u16* ql = p; p += (size_t)SEQ * DINNER;
    u16* kh = p; p += (size_t)SEQ * DINNER;
    u16* kl = p; p += (size_t)SEQ * DINNER;
    u16* vt = p; p += (size_t)DINNER * SEQ;
    u16* atto = p; p += (size_t)SEQ * DINNER;

    // split-KV partials: 2304 chunk-tiles x 16KB fp32. Tiles 0..1023 in d_out (exact 16.78MB),
    // 1024..1407 in the dead wqt_h/wqt_l region (exact 6.29MB), 1408..2303 + ml in ws.
    float* po_dout = (float*)d_out;
    float* po_wqt  = (float*)wqt_h;
    float* po_ws   = (float*)p;
    float* ml      = po_ws + (size_t)896 * 4096;
    const size_t need = (size_t)((char*)(ml + (size_t)2304 * 128) - (char*)d_ws);  // ~47 MB
    const bool split = ws_size >= need;

    transpose_split<<<dim3(QKVW / 64, DIM / 64), 256, 0, stream>>>(w_qkv, wqt_h, wqt_l,
                                                                   DIM, QKVW, 1);
    transpose_split<<<dim3(DIM / 64, DINNER / 64), 256, 0, stream>>>(w_out, wot, nullptr,
                                                                     DINNER, DIM, 0);
    rmsnorm_split<<<SEQ, 256, 0, stream>>>(x, gamma, nh, nl);
    gemm_qkv_split<<<dim3(QKVW / 64, SEQ / 64), 256, 0, stream>>>(nh, nl, wqt_h, wqt_l,
                                                                  qh, ql, kh, kl, vt);
    if (split) {
        attn_chunk<<<dim3(512, HEADS), 256, 0, stream>>>(qh, ql, kh, kl, vt,
                                                         po_dout, po_wqt, po_ws, ml);
        attn_merge<<<dim3(SEQ / 64, HEADS), 256, 0, stream>>>(po_dout, po_wqt, po_ws, ml, atto);
    } else {
        attn_mfma<<<dim3(SEQ / 64, HEADS), 256, 0, stream>>>(qh, ql, kh, kl, vt, atto);
    }
    gemm_out_bf16<<<dim3(DIM / 64, SEQ / 64), 256, 0, stream>>>(atto, wot, out);
}

// Round 4
// 296.290 us; speedup vs baseline: 1.1191x; 1.1191x over previous
//
#include <hip/hip_runtime.h>
#include <math.h>

#define SEQ 4096
#define DIM 1024
#define HEADS 8
#define DINNER 512
#define QKVW 1536
#define PAD 80   // LDS row stride in bf16 elems for attn tiles
#define CHUNK 16 // K-tiles (of 64) per split-KV chunk

typedef unsigned short u16;
typedef __attribute__((ext_vector_type(8))) short s8v;   // 8 bf16 (4 VGPRs)
typedef __attribute__((ext_vector_type(4))) float f4v;   // 4 fp32 acc
#define MFMA(a, b, c) __builtin_amdgcn_mfma_f32_16x16x32_bf16(a, b, c, 0, 0, 0)

__device__ __forceinline__ u16 f2bf(float f) {
    unsigned u = __float_as_uint(f);
    u += 0x7fff + ((u >> 16) & 1);   // RNE
    return (u16)(u >> 16);
}
__device__ __forceinline__ float bf2f(u16 b) { return __uint_as_float(((unsigned)b) << 16); }

// async global->LDS, 16B per lane. Dest is wave-uniform base + lane*16 (HW rule);
// source address is per-lane (pre-swizzled to realize the LDS XOR swizzle).
__device__ __forceinline__ void gload16(const u16* g, u16* l) {
    __builtin_amdgcn_global_load_lds(
        (const __attribute__((address_space(1))) unsigned int*)g,
        (__attribute__((address_space(3))) unsigned int*)l, 16, 0, 0);
}

// chunk-tile flat index: T = h*160 + base16(qt) + c; nc(qt) = qt/16 + 1
__device__ __forceinline__ int base16(int qt) {
    int a = qt >> 4, b = qt & 15;
    return 8 * a * (a + 1) + b * (a + 1);
}
// partials: tiles 0..1023 in d_out, 1024..1279 in the dead wqt region
__device__ __forceinline__ float* po_sel(int T, float* pd, float* pw) {
    return (T < 1024) ? pd + (size_t)T * 4096 : pw + (size_t)(T - 1024) * 4096;
}

// ---------- RMSNorm -> split bf16 (hi, lo) ----------
__global__ __launch_bounds__(256) void rmsnorm_split(const float* __restrict__ x,
                                                     const float* __restrict__ gamma,
                                                     u16* __restrict__ hi,
                                                     u16* __restrict__ lo) {
    __shared__ float red[4];
    const int row = blockIdx.x, t = threadIdx.x;
    const float* xr = x + (size_t)row * DIM;
    float v[4];
    float ss = 0.f;
#pragma unroll
    for (int i = 0; i < 4; ++i) { v[i] = xr[t + i * 256]; ss += v[i] * v[i]; }
#pragma unroll
    for (int off = 32; off >= 1; off >>= 1) ss += __shfl_xor(ss, off, 64);
    if ((t & 63) == 0) red[t >> 6] = ss;
    __syncthreads();
    float scale = 32.0f / fmaxf(sqrtf(red[0] + red[1] + red[2] + red[3]), 1e-12f);
#pragma unroll
    for (int i = 0; i < 4; ++i) {
        int c = t + i * 256;
        float y = v[i] * scale * gamma[c];
        u16 h = f2bf(y);
        hi[(size_t)row * DIM + c] = h;
        lo[(size_t)row * DIM + c] = f2bf(y - bf2f(h));
    }
}

// ---------- transpose fp32 [R][C] -> bf16 hi/lo [C][R] ----------
__global__ __launch_bounds__(256) void transpose_split(const float* __restrict__ in,
                                                       u16* __restrict__ hi,
                                                       u16* __restrict__ lo,
                                                       int R, int C, int want_lo) {
    __shared__ float tile[64][65];
    const int c0 = blockIdx.x * 64, r0 = blockIdx.y * 64;
    const int t = threadIdx.x, col = t & 63, rb = t >> 6;
#pragma unroll
    for (int j = 0; j < 16; ++j)
        tile[rb + j * 4][col] = in[(size_t)(r0 + rb + j * 4) * C + c0 + col];
    __syncthreads();
#pragma unroll
    for (int j = 0; j < 16; ++j) {
        int cc = rb + j * 4;
        float v = tile[col][cc];
        size_t oi = (size_t)(c0 + cc) * R + r0 + col;
        u16 h = f2bf(v);
        hi[oi] = h;
        if (want_lo) lo[oi] = f2bf(v - bf2f(h));
    }
}

// ---------- QKV GEMM: 128x64 tile, global_load_lds staging, XOR-swizzled LDS ----------
// A: normed hi/lo [4096][1024]; B: w_qkv^T hi/lo [1536][1024]. C tile 128(M) x 64(N).
// LDS linear [rows][64] bf16 (128B rows). Swizzle: byte_in_row ^= (row&7)<<4, realized as
// pre-swizzled global SOURCE column (linear LDS dest, rule #21) + swizzled ds_read addr.
// 768 blocks = exactly 3/CU (48KB LDS). Wave (wr=w>>1, wc=w&1) owns 64x32; acc[4][2].
__global__ __launch_bounds__(256) void gemm_qkv_128(
    const u16* __restrict__ Ah, const u16* __restrict__ Al,
    const u16* __restrict__ Bh, const u16* __restrict__ Bl,
    u16* __restrict__ qh, u16* __restrict__ ql,
    u16* __restrict__ kh, u16* __restrict__ kl, u16* __restrict__ vtp) {
    __shared__ __align__(16) u16 AsH[128 * 64], AsL[128 * 64];
    __shared__ __align__(16) u16 BsH[64 * 64], BsL[64 * 64];
    const int t = threadIdx.x;
    const int bn = blockIdx.x * 64, bm = blockIdx.y * 128;
    const int w = t >> 6, lane = t & 63, m = lane & 15, q = lane >> 4;
    const int wr = w >> 1, wc = w & 1;
    f4v acc[4][2];
#pragma unroll
    for (int i = 0; i < 4; ++i)
#pragma unroll
        for (int j = 0; j < 2; ++j) acc[i][j] = (f4v){0.f, 0.f, 0.f, 0.f};

    for (int k0 = 0; k0 < DIM; k0 += 64) {
        __syncthreads();
        // A tiles: 128 rows -> 4 passes; B tiles: 64 rows -> 2 passes. 16B/lane each.
#pragma unroll
        for (int i = 0; i < 4; ++i) {
            int idx0 = i * 256 + w * 64;              // wave-uniform LDS base (x8 u16 = x16B)
            int row = (idx0 + lane) >> 3;
            int col = ((lane & 7) * 8) ^ ((row & 7) * 8);   // pre-swizzled source column
            gload16(&Ah[(size_t)(bm + row) * DIM + k0 + col], &AsH[idx0 * 8]);
            gload16(&Al[(size_t)(bm + row) * DIM + k0 + col], &AsL[idx0 * 8]);
            if (i < 2) {
                gload16(&Bh[(size_t)(bn + row) * DIM + k0 + col], &BsH[idx0 * 8]);
                gload16(&Bl[(size_t)(bn + row) * DIM + k0 + col], &BsL[idx0 * 8]);
            }
        }
        __syncthreads();   // compiler drains vmcnt(0) here
#pragma unroll
        for (int kk = 0; kk < 64; kk += 32) {
            s8v a_h[4], a_l[4], b_h[2], b_l[2];
#pragma unroll
            for (int f = 0; f < 4; ++f) {
                int ar = wr * 64 + f * 16 + m;
                int ab = ar * 128 + (((kk + q * 8) * 2) ^ ((ar & 7) << 4));
                a_h[f] = *(const s8v*)((const char*)AsH + ab);
                a_l[f] = *(const s8v*)((const char*)AsL + ab);
            }
#pragma unroll
            for (int f = 0; f < 2; ++f) {
                int br = wc * 32 + f * 16 + m;
                int bb = br * 128 + (((kk + q * 8) * 2) ^ ((br & 7) << 4));
                b_h[f] = *(const s8v*)((const char*)BsH + bb);
                b_l[f] = *(const s8v*)((const char*)BsL + bb);
            }
#pragma unroll
            for (int fm = 0; fm < 4; ++fm)
#pragma unroll
                for (int fn = 0; fn < 2; ++fn) {
                    acc[fm][fn] = MFMA(a_h[fm], b_h[fn], acc[fm][fn]);
                    acc[fm][fn] = MFMA(a_l[fm], b_h[fn], acc[fm][fn]);
                    acc[fm][fn] = MFMA(a_h[fm], b_l[fn], acc[fm][fn]);
                }
        }
    }
    const int region = bn >> 9;   // uniform per block (bn multiple of 64)
#pragma unroll
    for (int fm = 0; fm < 4; ++fm)
#pragma unroll
        for (int fn = 0; fn < 2; ++fn)
#pragma unroll
            for (int r = 0; r < 4; ++r) {
                int gr = bm + wr * 64 + fm * 16 + q * 4 + r;
                int gc = bn + wc * 32 + fn * 16 + m;
                float v = acc[fm][fn][r];
                if (region == 0) {
                    v *= 8.0f;   // q * sqrt(d), faithful to reference
                    u16 h = f2bf(v);
                    qh[(size_t)gr * DINNER + gc] = h;
                    ql[(size_t)gr * DINNER + gc] = f2bf(v - bf2f(h));
                } else if (region == 1) {
                    u16 h = f2bf(v);
                    kh[(size_t)gr * DINNER + (gc - 512)] = h;
                    kl[(size_t)gr * DINNER + (gc - 512)] = f2bf(v - bf2f(h));
                } else {
                    vtp[(size_t)(gc - 1024) * SEQ + gr] = f2bf(v);
                }
            }
}

// ---------- split-KV flash attention chunk kernel, swapped QK^T ----------
__global__ __launch_bounds__(256) void attn_chunk(
    const u16* __restrict__ qhp, const u16* __restrict__ qlp,
    const u16* __restrict__ kh, const u16* __restrict__ kl,
    const u16* __restrict__ vt,
    float* __restrict__ po_dout, float* __restrict__ po_wqt,
    float* __restrict__ ml) {
    __shared__ u16 KP[64 * PAD], Kl[64 * PAD], Vt[64 * PAD];
    const int t = threadIdx.x;
    const int bx = blockIdx.x;
    const int qt = 63 - (bx >> 2), c = bx & 3, h = blockIdx.y;
    if (c * CHUNK > qt) return;
    const int kt0 = c * CHUNK;
    const int kt1 = (qt < kt0 + CHUNK - 1) ? qt : (kt0 + CHUNK - 1);
    const int w = t >> 6, lane = t & 63, m = lane & 15, g = lane >> 4;

    // Q fragments in registers: row = qt*64 + w*16 + m, d-cols g*8 (+0 / +32)
    const size_t qrow = (size_t)(qt * 64 + w * 16 + m) * DINNER + h * 64;
    const s8v qf_h0 = *(const s8v*)&qhp[qrow + g * 8];
    const s8v qf_h1 = *(const s8v*)&qhp[qrow + 32 + g * 8];
    const s8v qf_l0 = *(const s8v*)&qlp[qrow + g * 8];
    const s8v qf_l1 = *(const s8v*)&qlp[qrow + 32 + g * 8];

    f4v o[4] = {{0.f, 0.f, 0.f, 0.f}, {0.f, 0.f, 0.f, 0.f},
                {0.f, 0.f, 0.f, 0.f}, {0.f, 0.f, 0.f, 0.f}};
    float mi_s = -1e30f, li_s = 0.f;   // per-lane stats for q = w*16 + m

    for (int kt = kt0; kt <= kt1; ++kt) {
        __syncthreads();   // prior iteration's P/Vt consumers done
#pragma unroll
        for (int i = 0; i < 2; ++i) {
            int c2 = t + i * 256, row = c2 >> 3, ch = (c2 & 7) * 8;
            *(uint4*)&KP[row * PAD + ch] =
                *(const uint4*)&kh[(size_t)(kt * 64 + row) * DINNER + h * 64 + ch];
            *(uint4*)&Kl[row * PAD + ch] =
                *(const uint4*)&kl[(size_t)(kt * 64 + row) * DINNER + h * 64 + ch];
            *(uint4*)&Vt[row * PAD + ch] =
                *(const uint4*)&vt[(size_t)(h * 64 + row) * SEQ + kt * 64 + ch];
        }
        __syncthreads();

        // S^T: s[ct][r] = S[q=w*16+m][kv=ct*16+g*4+r]; 3 MFMAs per 16x16x32 (split bf16)
        f4v s[4] = {{0.f, 0.f, 0.f, 0.f}, {0.f, 0.f, 0.f, 0.f},
                    {0.f, 0.f, 0.f, 0.f}, {0.f, 0.f, 0.f, 0.f}};
#pragma unroll
        for (int ct = 0; ct < 4; ++ct) {
            s8v bh0 = *(const s8v*)&KP[(ct * 16 + m) * PAD + g * 8];
            s8v bl0 = *(const s8v*)&Kl[(ct * 16 + m) * PAD + g * 8];
            s[ct] = MFMA(bh0, qf_h0, s[ct]);
            s[ct] = MFMA(bh0, qf_l0, s[ct]);
            s[ct] = MFMA(bl0, qf_h0, s[ct]);
            s8v bh1 = *(const s8v*)&KP[(ct * 16 + m) * PAD + 32 + g * 8];
            s8v bl1 = *(const s8v*)&Kl[(ct * 16 + m) * PAD + 32 + g * 8];
            s[ct] = MFMA(bh1, qf_h1, s[ct]);
            s[ct] = MFMA(bh1, qf_l1, s[ct]);
            s[ct] = MFMA(bl1, qf_h1, s[ct]);
        }
        if (kt == qt) {   // causal: mask kv > q (tile-local)
#pragma unroll
            for (int ct = 0; ct < 4; ++ct)
#pragma unroll
                for (int r = 0; r < 4; ++r)
                    if (ct * 16 + g * 4 + r > w * 16 + m) s[ct][r] = -1e30f;
        }

        // lane-local online softmax for q = w*16+m (16 kv values per lane)
        float rm = -1e30f;
#pragma unroll
        for (int ct = 0; ct < 4; ++ct)
#pragma unroll
            for (int r = 0; r < 4; ++r) rm = fmaxf(rm, s[ct][r]);
        rm = fmaxf(rm, __shfl_xor(rm, 16, 64));
        rm = fmaxf(rm, __shfl_xor(rm, 32, 64));
        float mn = fmaxf(mi_s, rm);
        float al = __expf(mi_s - mn);
        mi_s = mn;
        float rs = 0.f;
#pragma unroll
        for (int ct = 0; ct < 4; ++ct)
#pragma unroll
            for (int r = 0; r < 4; ++r) {
                s[ct][r] = __expf(s[ct][r] - mn);
                rs += s[ct][r];
            }
        rs += __shfl_xor(rs, 16, 64);
        rs += __shfl_xor(rs, 32, 64);
        li_s = li_s * al + rs;
        // alpha for o rows (q_local = g*4+r) lives at lane m == q_local
        float alo[4];
#pragma unroll
        for (int r = 0; r < 4; ++r) alo[r] = __shfl(al, g * 4 + r, 64);

        __syncthreads();   // all waves done reading KP as K-hi before P overwrite
#pragma unroll
        for (int ct = 0; ct < 4; ++ct) {
            unsigned w0 = (unsigned)f2bf(s[ct][0]) | ((unsigned)f2bf(s[ct][1]) << 16);
            unsigned w1 = (unsigned)f2bf(s[ct][2]) | ((unsigned)f2bf(s[ct][3]) << 16);
            *(uint2*)&KP[(w * 16 + m) * PAD + ct * 16 + g * 4] = make_uint2(w0, w1);
        }
#pragma unroll
        for (int ct = 0; ct < 4; ++ct)
#pragma unroll
            for (int r = 0; r < 4; ++r) o[ct][r] *= alo[r];
        // PV: each wave reads only its own P rows -> no barrier needed
#pragma unroll
        for (int kk = 0; kk < 64; kk += 32) {
            s8v ap = *(const s8v*)&KP[(w * 16 + m) * PAD + kk + g * 8];
#pragma unroll
            for (int ct = 0; ct < 4; ++ct) {
                s8v bv = *(const s8v*)&Vt[(ct * 16 + m) * PAD + kk + g * 8];
                o[ct] = MFMA(ap, bv, o[ct]);
            }
        }
    }

    // epilogue: raw partial o (fp32) + per-row (m, l)
    const int T = h * 160 + base16(qt) + c;
    float* po = po_sel(T, po_dout, po_wqt);
#pragma unroll
    for (int ct = 0; ct < 4; ++ct)
#pragma unroll
        for (int r = 0; r < 4; ++r)
            po[(size_t)(w * 16 + g * 4 + r) * 64 + ct * 16 + m] = o[ct][r];
    if (g == 0) {
        ml[(size_t)T * 128 + w * 16 + m] = mi_s;
        ml[(size_t)T * 128 + 64 + w * 16 + m] = li_s;
    }
}

// ---------- merge split-KV partials -> atto bf16 ----------
__global__ __launch_bounds__(256) void attn_merge(
    float* __restrict__ po_dout, float* __restrict__ po_wqt,
    const float* __restrict__ ml, u16* __restrict__ atto) {
    const int qt = blockIdx.x, h = blockIdx.y;
    const int nc = (qt >> 4) + 1;
    const int t = threadIdx.x, col = t & 63, rg = t >> 6;
    const int T0 = h * 160 + base16(qt);
    for (int j = 0; j < 16; ++j) {
        int row = rg * 16 + j;
        float mv[4], lv[4], M = -1e30f;
#pragma unroll 4
        for (int cc = 0; cc < 4; ++cc)
            if (cc < nc) {
                mv[cc] = ml[(size_t)(T0 + cc) * 128 + row];
                lv[cc] = ml[(size_t)(T0 + cc) * 128 + 64 + row];
                M = fmaxf(M, mv[cc]);
            }
        float acc = 0.f, den = 0.f;
#pragma unroll 4
        for (int cc = 0; cc < 4; ++cc)
            if (cc < nc) {
                const float* po = po_sel(T0 + cc, po_dout, po_wqt);
                float wg = __expf(mv[cc] - M);
                den += lv[cc] * wg;
                acc += wg * po[(size_t)row * 64 + col];
            }
        atto[(size_t)(qt * 64 + row) * DINNER + h * 64 + col] = f2bf(acc / den);
    }
}

// ---------- fallback: original fused flash attention (used if workspace too small) ----------
__global__ __launch_bounds__(256) void attn_mfma(
    const u16* __restrict__ qh, const u16* __restrict__ ql,
    const u16* __restrict__ kh, const u16* __restrict__ kl,
    const u16* __restrict__ vt, u16* __restrict__ atto) {
    __shared__ u16 Qh[64 * PAD], Ql[64 * PAD], KP[64 * PAD], Kl[64 * PAD], Vt[64 * PAD];
    const int t = threadIdx.x;
    const int qt = blockIdx.x, h = blockIdx.y;
    const int w = t >> 6, lane = t & 63, m = lane & 15, q = lane >> 4;

#pragma unroll
    for (int i = 0; i < 2; ++i) {
        int c = t + i * 256, row = c >> 3, ch = (c & 7) * 8;
        *(uint4*)&Qh[row * PAD + ch] =
            *(const uint4*)&qh[(size_t)(qt * 64 + row) * DINNER + h * 64 + ch];
        *(uint4*)&Ql[row * PAD + ch] =
            *(const uint4*)&ql[(size_t)(qt * 64 + row) * DINNER + h * 64 + ch];
    }

    f4v o[4] = {{0.f, 0.f, 0.f, 0.f}, {0.f, 0.f, 0.f, 0.f},
                {0.f, 0.f, 0.f, 0.f}, {0.f, 0.f, 0.f, 0.f}};
    float mi[4] = {-1e30f, -1e30f, -1e30f, -1e30f};
    float li[4] = {0.f, 0.f, 0.f, 0.f};

    for (int kt = 0; kt <= qt; ++kt) {
        __syncthreads();
#pragma unroll
        for (int i = 0; i < 2; ++i) {
            int c = t + i * 256, row = c >> 3, ch = (c & 7) * 8;
            *(uint4*)&KP[row * PAD + ch] =
                *(const uint4*)&kh[(size_t)(kt * 64 + row) * DINNER + h * 64 + ch];
            *(uint4*)&Kl[row * PAD + ch] =
                *(const uint4*)&kl[(size_t)(kt * 64 + row) * DINNER + h * 64 + ch];
            *(uint4*)&Vt[row * PAD + ch] =
                *(const uint4*)&vt[(size_t)(h * 64 + row) * SEQ + kt * 64 + ch];
        }
        __syncthreads();

        f4v s[4] = {{0.f, 0.f, 0.f, 0.f}, {0.f, 0.f, 0.f, 0.f},
                    {0.f, 0.f, 0.f, 0.f}, {0.f, 0.f, 0.f, 0.f}};
#pragma unroll
        for (int kk = 0; kk < 64; kk += 32) {
            s8v ah = *(const s8v*)&Qh[(w * 16 + m) * PAD + kk + q * 8];
            s8v al = *(const s8v*)&Ql[(w * 16 + m) * PAD + kk + q * 8];
#pragma unroll
            for (int ct = 0; ct < 4; ++ct) {
                s8v bh = *(const s8v*)&KP[(ct * 16 + m) * PAD + kk + q * 8];
                s8v bl = *(const s8v*)&Kl[(ct * 16 + m) * PAD + kk + q * 8];
                s[ct] = MFMA(ah, bh, s[ct]);
                s[ct] = MFMA(al, bh, s[ct]);
                s[ct] = MFMA(ah, bl, s[ct]);
            }
        }
        if (kt == qt) {
#pragma unroll
            for (int ct = 0; ct < 4; ++ct)
#pragma unroll
                for (int r = 0; r < 4; ++r)
                    if (ct * 16 + m > w * 16 + q * 4 + r) s[ct][r] = -1e30f;
        }

        float alpha[4];
#pragma unroll
        for (int r = 0; r < 4; ++r) {
            float rm = fmaxf(fmaxf(s[0][r], s[1][r]), fmaxf(s[2][r], s[3][r]));
#pragma unroll
            for (int off = 8; off >= 1; off >>= 1) rm = fmaxf(rm, __shfl_xor(rm, off, 64));
            float mn = fmaxf(mi[r], rm);
            alpha[r] = __expf(mi[r] - mn);
            mi[r] = mn;
            float rs = 0.f;
#pragma unroll
            for (int ct = 0; ct < 4; ++ct) {
                s[ct][r] = __expf(s[ct][r] - mn);
                rs += s[ct][r];
            }
#pragma unroll
            for (int off = 8; off >= 1; off >>= 1) rs += __shfl_xor(rs, off, 64);
            li[r] = li[r] * alpha[r] + rs;
        }

        __syncthreads();
#pragma unroll
        for (int ct = 0; ct < 4; ++ct)
#pragma unroll
            for (int r = 0; r < 4; ++r) {
                KP[(w * 16 + q * 4 + r) * PAD + ct * 16 + m] = f2bf(s[ct][r]);
                o[ct][r] *= alpha[r];
            }
#pragma unroll
        for (int kk = 0; kk < 64; kk += 32) {
            s8v ap = *(const s8v*)&KP[(w * 16 + m) * PAD + kk + q * 8];
#pragma unroll
            for (int ct = 0; ct < 4; ++ct) {
                s8v bv = *(const s8v*)&Vt[(ct * 16 + m) * PAD + kk + q * 8];
                o[ct] = MFMA(ap, bv, o[ct]);
            }
        }
    }

#pragma unroll
    for (int r = 0; r < 4; ++r) {
        float inv = 1.0f / li[r];
#pragma unroll
        for (int ct = 0; ct < 4; ++ct)
            atto[(size_t)(qt * 64 + w * 16 + q * 4 + r) * DINNER + h * 64 + ct * 16 + m] =
                f2bf(o[ct][r] * inv);
    }
}

// ---------- out projection: atto bf16 [4096][512] @ w_out^T bf16 [1024][512] -> fp32 ----------
__global__ __launch_bounds__(256) void gemm_out_bf16(const u16* __restrict__ A,
                                                     const u16* __restrict__ Bt,
                                                     float* __restrict__ C) {
    __shared__ u16 As[64 * PAD], Bs[64 * PAD];
    const int t = threadIdx.x;
    const int bn = blockIdx.x * 64, bm = blockIdx.y * 64;
    const int w = t >> 6, lane = t & 63, m = lane & 15, q = lane >> 4;
    f4v acc[4] = {{0.f, 0.f, 0.f, 0.f}, {0.f, 0.f, 0.f, 0.f},
                  {0.f, 0.f, 0.f, 0.f}, {0.f, 0.f, 0.f, 0.f}};
    for (int k0 = 0; k0 < DINNER; k0 += 64) {
        __syncthreads();
#pragma unroll
        for (int i = 0; i < 2; ++i) {
            int c = t + i * 256, row = c >> 3, ch = (c & 7) * 8;
            *(uint4*)&As[row * PAD + ch] = *(const uint4*)&A[(size_t)(bm + row) * DINNER + k0 + ch];
            *(uint4*)&Bs[row * PAD + ch] = *(const uint4*)&Bt[(size_t)(bn + row) * DINNER + k0 + ch];
        }
        __syncthreads();
#pragma unroll
        for (int kk = 0; kk < 64; kk += 32) {
            s8v a = *(const s8v*)&As[(w * 16 + m) * PAD + kk + q * 8];
#pragma unroll
            for (int ct = 0; ct < 4; ++ct) {
                s8v b = *(const s8v*)&Bs[(ct * 16 + m) * PAD + kk + q * 8];
                acc[ct] = MFMA(a, b, acc[ct]);
            }
        }
    }
#pragma unroll
    for (int ct = 0; ct < 4; ++ct)
#pragma unroll
        for (int r = 0; r < 4; ++r)
            C[(size_t)(bm + w * 16 + q * 4 + r) * DIM + bn + ct * 16 + m] = acc[ct][r];
}

extern "C" void kernel_launch(void* const* d_in, const int* in_sizes, int n_in,
                              void* d_out, int out_size, void* d_ws, size_t ws_size,
                              hipStream_t stream) {
    const float* x     = (const float*)d_in[0];
    const float* gamma = (const float*)d_in[1];
    const float* w_qkv = (const float*)d_in[2];
    const float* w_out = (const float*)d_in[3];
    float* out = (float*)d_out;

    // normed hi/lo live in d_out (exact fit; consumed by gemm_qkv before partials overwrite)
    u16* nh = (u16*)d_out;
    u16* nl = nh + (size_t)SEQ * DIM;

    u16* p = (u16*)d_ws;
    u16* wqt_h = p; p += (size_t)QKVW * DIM;
    u16* wqt_l = p; p += (size_t)QKVW * DIM;
    u16* wot   = p; p += (size_t)DIM * DINNER;
    u16* qh = p; p += (size_t)SEQ * DINNER;
    u16* ql = p; p += (size_t)SEQ * DINNER;
    u16* kh = p; p += (size_t)SEQ * DINNER;
    u16* kl = p; p += (size_t)SEQ * DINNER;
    u16* vt = p; p += (size_t)DINNER * SEQ;
    u16* atto = p; p += (size_t)SEQ * DINNER;

    // split-KV partials: 1280 chunk-tiles x 16KB fp32. Tiles 0..1023 in d_out (16.78MB),
    // 1024..1279 in the dead wqt_h/wqt_l region (4.19MB of 6.29MB). ml in ws.
    float* po_dout = (float*)d_out;
    float* po_wqt  = (float*)wqt_h;
    float* ml      = (float*)p;
    const size_t need = (size_t)((char*)(ml + (size_t)1280 * 128) - (char*)d_ws);  // ~32 MB
    const bool split = ws_size >= need;

    transpose_split<<<dim3(QKVW / 64, DIM / 64), 256, 0, stream>>>(w_qkv, wqt_h, wqt_l,
                                                                   DIM, QKVW, 1);
    transpose_split<<<dim3(DIM / 64, DINNER / 64), 256, 0, stream>>>(w_out, wot, nullptr,
                                                                     DINNER, DIM, 0);
    rmsnorm_split<<<SEQ, 256, 0, stream>>>(x, gamma, nh, nl);
    gemm_qkv_128<<<dim3(QKVW / 64, SEQ / 128), 256, 0, stream>>>(nh, nl, wqt_h, wqt_l,
                                                                 qh, ql, kh, kl, vt);
    if (split) {
        attn_chunk<<<dim3(256, HEADS), 256, 0, stream>>>(qh, ql, kh, kl, vt,
                                                         po_dout, po_wqt, ml);
        attn_merge<<<dim3(SEQ / 64, HEADS), 256, 0, stream>>>(po_dout, po_wqt, ml, atto);
    } else {
        attn_mfma<<<dim3(SEQ / 64, HEADS), 256, 0, stream>>>(qh, ql, kh, kl, vt, atto);
    }
    gemm_out_bf16<<<dim3(DIM / 64, SEQ / 64), 256, 0, stream>>>(atto, wot, out);
}

// Round 5
// 293.939 us; speedup vs baseline: 1.1281x; 1.0080x over previous
//
#include <hip/hip_runtime.h>
#include <math.h>

#define SEQ 4096
#define DIM 1024
#define HEADS 8
#define DINNER 512
#define QKVW 1536
#define PAD 80   // LDS row stride (bf16 elems) for legacy fallback kernels
#define CHUNK 16 // K-tiles (of 64) per split-KV chunk

typedef unsigned short u16;
typedef __attribute__((ext_vector_type(8))) short s8v;   // 8 bf16 (4 VGPRs)
typedef __attribute__((ext_vector_type(4))) float f4v;   // 4 fp32 acc
#define MFMA(a, b, c) __builtin_amdgcn_mfma_f32_16x16x32_bf16(a, b, c, 0, 0, 0)

__device__ __forceinline__ u16 f2bf(float f) {
    unsigned u = __float_as_uint(f);
    u += 0x7fff + ((u >> 16) & 1);   // RNE
    return (u16)(u >> 16);
}
__device__ __forceinline__ float bf2f(u16 b) { return __uint_as_float(((unsigned)b) << 16); }

// async global->LDS, 16B per lane. LDS dest is wave-uniform base + lane*16 (HW rule);
// the GLOBAL source is per-lane and pre-swizzled to realize the LDS XOR swizzle (rule #21).
__device__ __forceinline__ void gload16(const u16* g, u16* l) {
    __builtin_amdgcn_global_load_lds(
        (const __attribute__((address_space(1))) unsigned int*)g,
        (__attribute__((address_space(3))) unsigned int*)l, 16, 0, 0);
}

// chunk-tile flat index: T = h*160 + base16(qt) + c; nc(qt) = qt/16 + 1
__device__ __forceinline__ int base16(int qt) {
    int a = qt >> 4, b = qt & 15;
    return 8 * a * (a + 1) + b * (a + 1);
}
// partials: tiles 0..1023 in d_out, 1024..1279 in the dead wqt region
__device__ __forceinline__ float* po_sel(int T, float* pd, float* pw) {
    return (T < 1024) ? pd + (size_t)T * 4096 : pw + (size_t)(T - 1024) * 4096;
}

// ---------- RMSNorm -> split bf16 (hi, lo) ----------
__global__ __launch_bounds__(256) void rmsnorm_split(const float* __restrict__ x,
                                                     const float* __restrict__ gamma,
                                                     u16* __restrict__ hi,
                                                     u16* __restrict__ lo) {
    __shared__ float red[4];
    const int row = blockIdx.x, t = threadIdx.x;
    const float* xr = x + (size_t)row * DIM;
    float v[4];
    float ss = 0.f;
#pragma unroll
    for (int i = 0; i < 4; ++i) { v[i] = xr[t + i * 256]; ss += v[i] * v[i]; }
#pragma unroll
    for (int off = 32; off >= 1; off >>= 1) ss += __shfl_xor(ss, off, 64);
    if ((t & 63) == 0) red[t >> 6] = ss;
    __syncthreads();
    float scale = 32.0f / fmaxf(sqrtf(red[0] + red[1] + red[2] + red[3]), 1e-12f);
#pragma unroll
    for (int i = 0; i < 4; ++i) {
        int c = t + i * 256;
        float y = v[i] * scale * gamma[c];
        u16 h = f2bf(y);
        hi[(size_t)row * DIM + c] = h;
        lo[(size_t)row * DIM + c] = f2bf(y - bf2f(h));
    }
}

// ---------- transpose fp32 [R][C] -> bf16 hi/lo [C][R] ----------
__global__ __launch_bounds__(256) void transpose_split(const float* __restrict__ in,
                                                       u16* __restrict__ hi,
                                                       u16* __restrict__ lo,
                                                       int R, int C, int want_lo) {
    __shared__ float tile[64][65];
    const int c0 = blockIdx.x * 64, r0 = blockIdx.y * 64;
    const int t = threadIdx.x, col = t & 63, rb = t >> 6;
#pragma unroll
    for (int j = 0; j < 16; ++j)
        tile[rb + j * 4][col] = in[(size_t)(r0 + rb + j * 4) * C + c0 + col];
    __syncthreads();
#pragma unroll
    for (int j = 0; j < 16; ++j) {
        int cc = rb + j * 4;
        float v = tile[col][cc];
        size_t oi = (size_t)(c0 + cc) * R + r0 + col;
        u16 h = f2bf(v);
        hi[oi] = h;
        if (want_lo) lo[oi] = f2bf(v - bf2f(h));
    }
}

// ---------- QKV GEMM: 128x64 tile, global_load_lds staging, XOR-swizzled LDS ----------
__global__ __launch_bounds__(256) void gemm_qkv_128(
    const u16* __restrict__ Ah, const u16* __restrict__ Al,
    const u16* __restrict__ Bh, const u16* __restrict__ Bl,
    u16* __restrict__ qh, u16* __restrict__ ql,
    u16* __restrict__ kh, u16* __restrict__ kl, u16* __restrict__ vtp) {
    __shared__ __align__(16) u16 AsH[128 * 64], AsL[128 * 64];
    __shared__ __align__(16) u16 BsH[64 * 64], BsL[64 * 64];
    const int t = threadIdx.x;
    const int bn = blockIdx.x * 64, bm = blockIdx.y * 128;
    const int w = t >> 6, lane = t & 63, m = lane & 15, q = lane >> 4;
    const int wr = w >> 1, wc = w & 1;
    f4v acc[4][2];
#pragma unroll
    for (int i = 0; i < 4; ++i)
#pragma unroll
        for (int j = 0; j < 2; ++j) acc[i][j] = (f4v){0.f, 0.f, 0.f, 0.f};

    for (int k0 = 0; k0 < DIM; k0 += 64) {
        __syncthreads();
#pragma unroll
        for (int i = 0; i < 4; ++i) {
            int idx0 = i * 256 + w * 64;              // wave-uniform LDS granule base
            int row = (idx0 + lane) >> 3;
            int col = ((lane & 7) * 8) ^ ((row & 7) * 8);   // pre-swizzled source column
            gload16(&Ah[(size_t)(bm + row) * DIM + k0 + col], &AsH[idx0 * 8]);
            gload16(&Al[(size_t)(bm + row) * DIM + k0 + col], &AsL[idx0 * 8]);
            if (i < 2) {
                gload16(&Bh[(size_t)(bn + row) * DIM + k0 + col], &BsH[idx0 * 8]);
                gload16(&Bl[(size_t)(bn + row) * DIM + k0 + col], &BsL[idx0 * 8]);
            }
        }
        __syncthreads();   // compiler drains vmcnt(0) here
#pragma unroll
        for (int kk = 0; kk < 64; kk += 32) {
            s8v a_h[4], a_l[4], b_h[2], b_l[2];
#pragma unroll
            for (int f = 0; f < 4; ++f) {
                int ar = wr * 64 + f * 16 + m;
                int ab = ar * 128 + (((kk + q * 8) * 2) ^ ((ar & 7) << 4));
                a_h[f] = *(const s8v*)((const char*)AsH + ab);
                a_l[f] = *(const s8v*)((const char*)AsL + ab);
            }
#pragma unroll
            for (int f = 0; f < 2; ++f) {
                int br = wc * 32 + f * 16 + m;
                int bb = br * 128 + (((kk + q * 8) * 2) ^ ((br & 7) << 4));
                b_h[f] = *(const s8v*)((const char*)BsH + bb);
                b_l[f] = *(const s8v*)((const char*)BsL + bb);
            }
#pragma unroll
            for (int fm = 0; fm < 4; ++fm)
#pragma unroll
                for (int fn = 0; fn < 2; ++fn) {
                    acc[fm][fn] = MFMA(a_h[fm], b_h[fn], acc[fm][fn]);
                    acc[fm][fn] = MFMA(a_l[fm], b_h[fn], acc[fm][fn]);
                    acc[fm][fn] = MFMA(a_h[fm], b_l[fn], acc[fm][fn]);
                }
        }
    }
    const int region = bn >> 9;   // uniform per block
#pragma unroll
    for (int fm = 0; fm < 4; ++fm)
#pragma unroll
        for (int fn = 0; fn < 2; ++fn)
#pragma unroll
            for (int r = 0; r < 4; ++r) {
                int gr = bm + wr * 64 + fm * 16 + q * 4 + r;
                int gc = bn + wc * 32 + fn * 16 + m;
                float v = acc[fm][fn][r];
                if (region == 0) {
                    v *= 8.0f;   // q * sqrt(d), faithful to reference
                    u16 h = f2bf(v);
                    qh[(size_t)gr * DINNER + gc] = h;
                    ql[(size_t)gr * DINNER + gc] = f2bf(v - bf2f(h));
                } else if (region == 1) {
                    u16 h = f2bf(v);
                    kh[(size_t)gr * DINNER + (gc - 512)] = h;
                    kl[(size_t)gr * DINNER + (gc - 512)] = f2bf(v - bf2f(h));
                } else {
                    vtp[(size_t)(gc - 1024) * SEQ + gr] = f2bf(v);
                }
            }
}

// ---------- split-KV flash attention, swapped QK^T, 2-phase double-buffered staging ----------
// T3 structure: stage(kt+1 -> buf^1) issues at iter top via global_load_lds (linear LDS dest,
// pre-swizzled global source), drains at the mid-barrier -- global latency hides under
// QK+softmax. All LDS accesses use byte ^= (row&7)<<4 (T2). P overwrites KH[cur] (dead
// after mid-barrier). LDS 48KB -> 3 blocks/CU. Two barriers/iter (P/K WAR + buffer WAR).
__global__ __launch_bounds__(256) void attn_chunk(
    const u16* __restrict__ qhp, const u16* __restrict__ qlp,
    const u16* __restrict__ kh, const u16* __restrict__ kl,
    const u16* __restrict__ vt,
    float* __restrict__ po_dout, float* __restrict__ po_wqt,
    float* __restrict__ ml) {
    __shared__ __align__(16) u16 KH[2][64 * 64], KL[2][64 * 64], VT[2][64 * 64];
    const int t = threadIdx.x;
    const int bx = blockIdx.x;
    const int qt = 63 - (bx >> 2), c = bx & 3, h = blockIdx.y;
    if (c * CHUNK > qt) return;
    const int kt0 = c * CHUNK;
    const int kt1 = (qt < kt0 + CHUNK - 1) ? qt : (kt0 + CHUNK - 1);
    const int w = t >> 6, lane = t & 63, m = lane & 15, g = lane >> 4;

    // Q fragments in registers: row = qt*64 + w*16 + m, d-cols g*8 (+0 / +32)
    const size_t qrow = (size_t)(qt * 64 + w * 16 + m) * DINNER + h * 64;
    const s8v qf_h0 = *(const s8v*)&qhp[qrow + g * 8];
    const s8v qf_h1 = *(const s8v*)&qhp[qrow + 32 + g * 8];
    const s8v qf_l0 = *(const s8v*)&qlp[qrow + g * 8];
    const s8v qf_l1 = *(const s8v*)&qlp[qrow + 32 + g * 8];

    // staging: 512 granules (16B) per 8KB tile = 2 gload16 per thread per array
    const int sg0a = w * 64, sg0b = 256 + w * 64;
    const int srowa = (sg0a + lane) >> 3, srowb = (sg0b + lane) >> 3;
    const int sca = ((lane & 7) ^ (srowa & 7)) * 8;   // pre-swizzled source col (elems)
    const int scb = ((lane & 7) ^ (srowb & 7)) * 8;

    f4v o[4] = {{0.f, 0.f, 0.f, 0.f}, {0.f, 0.f, 0.f, 0.f},
                {0.f, 0.f, 0.f, 0.f}, {0.f, 0.f, 0.f, 0.f}};
    float mi_s = -1e30f, li_s = 0.f;   // per-lane stats for q = w*16 + m

    // prologue: stage first tile into buf 0
    {
        const u16* kr = &kh[(size_t)(kt0 * 64) * DINNER + h * 64];
        const u16* lr = &kl[(size_t)(kt0 * 64) * DINNER + h * 64];
        const u16* vr = &vt[(size_t)(h * 64) * SEQ + kt0 * 64];
        gload16(kr + (size_t)srowa * DINNER + sca, &KH[0][sg0a * 8]);
        gload16(kr + (size_t)srowb * DINNER + scb, &KH[0][sg0b * 8]);
        gload16(lr + (size_t)srowa * DINNER + sca, &KL[0][sg0a * 8]);
        gload16(lr + (size_t)srowb * DINNER + scb, &KL[0][sg0b * 8]);
        gload16(vr + (size_t)srowa * SEQ + sca, &VT[0][sg0a * 8]);
        gload16(vr + (size_t)srowb * SEQ + scb, &VT[0][sg0b * 8]);
    }
    __syncthreads();   // drains vmcnt(0)

    int cur = 0;
    for (int kt = kt0; kt <= kt1; ++kt) {
        if (kt < kt1) {   // prefetch next tile into buf^1; hides under QK+softmax
            int nb = cur ^ 1;
            const u16* kr = &kh[(size_t)((kt + 1) * 64) * DINNER + h * 64];
            const u16* lr = &kl[(size_t)((kt + 1) * 64) * DINNER + h * 64];
            const u16* vr = &vt[(size_t)(h * 64) * SEQ + (kt + 1) * 64];
            gload16(kr + (size_t)srowa * DINNER + sca, &KH[nb][sg0a * 8]);
            gload16(kr + (size_t)srowb * DINNER + scb, &KH[nb][sg0b * 8]);
            gload16(lr + (size_t)srowa * DINNER + sca, &KL[nb][sg0a * 8]);
            gload16(lr + (size_t)srowb * DINNER + scb, &KL[nb][sg0b * 8]);
            gload16(vr + (size_t)srowa * SEQ + sca, &VT[nb][sg0a * 8]);
            gload16(vr + (size_t)srowb * SEQ + scb, &VT[nb][sg0b * 8]);
        }

        // S^T: s[ct][r] = S[q=w*16+m][kv=ct*16+g*4+r]; 3 MFMAs per 16x16x32 (split bf16)
        const char* KHc = (const char*)KH[cur];
        const char* KLc = (const char*)KL[cur];
        f4v s[4] = {{0.f, 0.f, 0.f, 0.f}, {0.f, 0.f, 0.f, 0.f},
                    {0.f, 0.f, 0.f, 0.f}, {0.f, 0.f, 0.f, 0.f}};
#pragma unroll
        for (int ct = 0; ct < 4; ++ct) {
            int rr = ct * 16 + m, rb = rr * 128, sw = (rr & 7) << 4;
            s8v bh0 = *(const s8v*)(KHc + rb + ((g * 16) ^ sw));
            s8v bl0 = *(const s8v*)(KLc + rb + ((g * 16) ^ sw));
            s[ct] = MFMA(bh0, qf_h0, s[ct]);
            s[ct] = MFMA(bh0, qf_l0, s[ct]);
            s[ct] = MFMA(bl0, qf_h0, s[ct]);
            s8v bh1 = *(const s8v*)(KHc + rb + ((64 + g * 16) ^ sw));
            s8v bl1 = *(const s8v*)(KLc + rb + ((64 + g * 16) ^ sw));
            s[ct] = MFMA(bh1, qf_h1, s[ct]);
            s[ct] = MFMA(bh1, qf_l1, s[ct]);
            s[ct] = MFMA(bl1, qf_h1, s[ct]);
        }
        if (kt == qt) {   // causal: mask kv > q (tile-local)
#pragma unroll
            for (int ct = 0; ct < 4; ++ct)
#pragma unroll
                for (int r = 0; r < 4; ++r)
                    if (ct * 16 + g * 4 + r > w * 16 + m) s[ct][r] = -1e30f;
        }

        // lane-local online softmax for q = w*16+m (16 kv values per lane)
        float rm = -1e30f;
#pragma unroll
        for (int ct = 0; ct < 4; ++ct)
#pragma unroll
            for (int r = 0; r < 4; ++r) rm = fmaxf(rm, s[ct][r]);
        rm = fmaxf(rm, __shfl_xor(rm, 16, 64));
        rm = fmaxf(rm, __shfl_xor(rm, 32, 64));
        float mn = fmaxf(mi_s, rm);
        float al = __expf(mi_s - mn);
        mi_s = mn;
        float rs = 0.f;
#pragma unroll
        for (int ct = 0; ct < 4; ++ct)
#pragma unroll
            for (int r = 0; r < 4; ++r) {
                s[ct][r] = __expf(s[ct][r] - mn);
                rs += s[ct][r];
            }
        rs += __shfl_xor(rs, 16, 64);
        rs += __shfl_xor(rs, 32, 64);
        li_s = li_s * al + rs;
        float alo[4];
#pragma unroll
        for (int r = 0; r < 4; ++r) alo[r] = __shfl(al, g * 4 + r, 64);

        __syncthreads();   // all waves done reading K[cur]; prefetch drains here

        // P -> KH[cur] (dead), swizzled; uint2 = 4 bf16 at linear col ct*16+g*4
        const int pr = w * 16 + m, pb = pr * 128, psw = (pr & 7) << 4;
#pragma unroll
        for (int ct = 0; ct < 4; ++ct) {
            unsigned w0 = (unsigned)f2bf(s[ct][0]) | ((unsigned)f2bf(s[ct][1]) << 16);
            unsigned w1 = (unsigned)f2bf(s[ct][2]) | ((unsigned)f2bf(s[ct][3]) << 16);
            *(uint2*)((char*)KH[cur] + pb + ((ct * 32 + g * 8) ^ psw)) = make_uint2(w0, w1);
        }
#pragma unroll
        for (int ct = 0; ct < 4; ++ct)
#pragma unroll
            for (int r = 0; r < 4; ++r) o[ct][r] *= alo[r];
        // PV: each wave reads only its own P rows -> no extra barrier
#pragma unroll
        for (int kk = 0; kk < 2; ++kk) {
            s8v ap = *(const s8v*)((const char*)KH[cur] + pb + ((kk * 64 + g * 16) ^ psw));
#pragma unroll
            for (int ct = 0; ct < 4; ++ct) {
                int vr2 = ct * 16 + m;
                s8v bv = *(const s8v*)((const char*)VT[cur] + vr2 * 128 +
                                       ((kk * 64 + g * 16) ^ ((vr2 & 7) << 4)));
                o[ct] = MFMA(ap, bv, o[ct]);
            }
        }
        __syncthreads();   // PV done across waves -> buf[cur] recyclable next iter
        cur ^= 1;
    }

    // epilogue: raw partial o (fp32) + per-row (m, l)
    const int T = h * 160 + base16(qt) + c;
    float* po = po_sel(T, po_dout, po_wqt);
#pragma unroll
    for (int ct = 0; ct < 4; ++ct)
#pragma unroll
        for (int r = 0; r < 4; ++r)
            po[(size_t)(w * 16 + g * 4 + r) * 64 + ct * 16 + m] = o[ct][r];
    if (g == 0) {
        ml[(size_t)T * 128 + w * 16 + m] = mi_s;
        ml[(size_t)T * 128 + 64 + w * 16 + m] = li_s;
    }
}

// ---------- merge split-KV partials -> atto bf16 ----------
__global__ __launch_bounds__(256) void attn_merge(
    float* __restrict__ po_dout, float* __restrict__ po_wqt,
    const float* __restrict__ ml, u16* __restrict__ atto) {
    const int qt = blockIdx.x, h = blockIdx.y;
    const int nc = (qt >> 4) + 1;
    const int t = threadIdx.x, col = t & 63, rg = t >> 6;
    const int T0 = h * 160 + base16(qt);
    for (int j = 0; j < 16; ++j) {
        int row = rg * 16 + j;
        float mv[4], lv[4], M = -1e30f;
#pragma unroll 4
        for (int cc = 0; cc < 4; ++cc)
            if (cc < nc) {
                mv[cc] = ml[(size_t)(T0 + cc) * 128 + row];
                lv[cc] = ml[(size_t)(T0 + cc) * 128 + 64 + row];
                M = fmaxf(M, mv[cc]);
            }
        float acc = 0.f, den = 0.f;
#pragma unroll 4
        for (int cc = 0; cc < 4; ++cc)
            if (cc < nc) {
                const float* po = po_sel(T0 + cc, po_dout, po_wqt);
                float wg = __expf(mv[cc] - M);
                den += lv[cc] * wg;
                acc += wg * po[(size_t)row * 64 + col];
            }
        atto[(size_t)(qt * 64 + row) * DINNER + h * 64 + col] = f2bf(acc / den);
    }
}

// ---------- fallback: original fused flash attention (used if workspace too small) ----------
__global__ __launch_bounds__(256) void attn_mfma(
    const u16* __restrict__ qh, const u16* __restrict__ ql,
    const u16* __restrict__ kh, const u16* __restrict__ kl,
    const u16* __restrict__ vt, u16* __restrict__ atto) {
    __shared__ u16 Qh[64 * PAD], Ql[64 * PAD], KP[64 * PAD], Kl[64 * PAD], Vt[64 * PAD];
    const int t = threadIdx.x;
    const int qt = blockIdx.x, h = blockIdx.y;
    const int w = t >> 6, lane = t & 63, m = lane & 15, q = lane >> 4;

#pragma unroll
    for (int i = 0; i < 2; ++i) {
        int c = t + i * 256, row = c >> 3, ch = (c & 7) * 8;
        *(uint4*)&Qh[row * PAD + ch] =
            *(const uint4*)&qh[(size_t)(qt * 64 + row) * DINNER + h * 64 + ch];
        *(uint4*)&Ql[row * PAD + ch] =
            *(const uint4*)&ql[(size_t)(qt * 64 + row) * DINNER + h * 64 + ch];
    }

    f4v o[4] = {{0.f, 0.f, 0.f, 0.f}, {0.f, 0.f, 0.f, 0.f},
                {0.f, 0.f, 0.f, 0.f}, {0.f, 0.f, 0.f, 0.f}};
    float mi[4] = {-1e30f, -1e30f, -1e30f, -1e30f};
    float li[4] = {0.f, 0.f, 0.f, 0.f};

    for (int kt = 0; kt <= qt; ++kt) {
        __syncthreads();
#pragma unroll
        for (int i = 0; i < 2; ++i) {
            int c = t + i * 256, row = c >> 3, ch = (c & 7) * 8;
            *(uint4*)&KP[row * PAD + ch] =
                *(const uint4*)&kh[(size_t)(kt * 64 + row) * DINNER + h * 64 + ch];
            *(uint4*)&Kl[row * PAD + ch] =
                *(const uint4*)&kl[(size_t)(kt * 64 + row) * DINNER + h * 64 + ch];
            *(uint4*)&Vt[row * PAD + ch] =
                *(const uint4*)&vt[(size_t)(h * 64 + row) * SEQ + kt * 64 + ch];
        }
        __syncthreads();

        f4v s[4] = {{0.f, 0.f, 0.f, 0.f}, {0.f, 0.f, 0.f, 0.f},
                    {0.f, 0.f, 0.f, 0.f}, {0.f, 0.f, 0.f, 0.f}};
#pragma unroll
        for (int kk = 0; kk < 64; kk += 32) {
            s8v ah = *(const s8v*)&Qh[(w * 16 + m) * PAD + kk + q * 8];
            s8v al = *(const s8v*)&Ql[(w * 16 + m) * PAD + kk + q * 8];
#pragma unroll
            for (int ct = 0; ct < 4; ++ct) {
                s8v bh = *(const s8v*)&KP[(ct * 16 + m) * PAD + kk + q * 8];
                s8v bl = *(const s8v*)&Kl[(ct * 16 + m) * PAD + kk + q * 8];
                s[ct] = MFMA(ah, bh, s[ct]);
                s[ct] = MFMA(al, bh, s[ct]);
                s[ct] = MFMA(ah, bl, s[ct]);
            }
        }
        if (kt == qt) {
#pragma unroll
            for (int ct = 0; ct < 4; ++ct)
#pragma unroll
                for (int r = 0; r < 4; ++r)
                    if (ct * 16 + m > w * 16 + q * 4 + r) s[ct][r] = -1e30f;
        }

        float alpha[4];
#pragma unroll
        for (int r = 0; r < 4; ++r) {
            float rm = fmaxf(fmaxf(s[0][r], s[1][r]), fmaxf(s[2][r], s[3][r]));
#pragma unroll
            for (int off = 8; off >= 1; off >>= 1) rm = fmaxf(rm, __shfl_xor(rm, off, 64));
            float mn = fmaxf(mi[r], rm);
            alpha[r] = __expf(mi[r] - mn);
            mi[r] = mn;
            float rs = 0.f;
#pragma unroll
            for (int ct = 0; ct < 4; ++ct) {
                s[ct][r] = __expf(s[ct][r] - mn);
                rs += s[ct][r];
            }
#pragma unroll
            for (int off = 8; off >= 1; off >>= 1) rs += __shfl_xor(rs, off, 64);
            li[r] = li[r] * alpha[r] + rs;
        }

        __syncthreads();
#pragma unroll
        for (int ct = 0; ct < 4; ++ct)
#pragma unroll
            for (int r = 0; r < 4; ++r) {
                KP[(w * 16 + q * 4 + r) * PAD + ct * 16 + m] = f2bf(s[ct][r]);
                o[ct][r] *= alpha[r];
            }
#pragma unroll
        for (int kk = 0; kk < 64; kk += 32) {
            s8v ap = *(const s8v*)&KP[(w * 16 + m) * PAD + kk + q * 8];
#pragma unroll
            for (int ct = 0; ct < 4; ++ct) {
                s8v bv = *(const s8v*)&Vt[(ct * 16 + m) * PAD + kk + q * 8];
                o[ct] = MFMA(ap, bv, o[ct]);
            }
        }
    }

#pragma unroll
    for (int r = 0; r < 4; ++r) {
        float inv = 1.0f / li[r];
#pragma unroll
        for (int ct = 0; ct < 4; ++ct)
            atto[(size_t)(qt * 64 + w * 16 + q * 4 + r) * DINNER + h * 64 + ct * 16 + m] =
                f2bf(o[ct][r] * inv);
    }
}

// ---------- out projection: atto bf16 [4096][512] @ w_out^T bf16 [1024][512] -> fp32 ----------
__global__ __launch_bounds__(256) void gemm_out_bf16(const u16* __restrict__ A,
                                                     const u16* __restrict__ Bt,
                                                     float* __restrict__ C) {
    __shared__ u16 As[64 * PAD], Bs[64 * PAD];
    const int t = threadIdx.x;
    const int bn = blockIdx.x * 64, bm = blockIdx.y * 64;
    const int w = t >> 6, lane = t & 63, m = lane & 15, q = lane >> 4;
    f4v acc[4] = {{0.f, 0.f, 0.f, 0.f}, {0.f, 0.f, 0.f, 0.f},
                  {0.f, 0.f, 0.f, 0.f}, {0.f, 0.f, 0.f, 0.f}};
    for (int k0 = 0; k0 < DINNER; k0 += 64) {
        __syncthreads();
#pragma unroll
        for (int i = 0; i < 2; ++i) {
            int c = t + i * 256, row = c >> 3, ch = (c & 7) * 8;
            *(uint4*)&As[row * PAD + ch] = *(const uint4*)&A[(size_t)(bm + row) * DINNER + k0 + ch];
            *(uint4*)&Bs[row * PAD + ch] = *(const uint4*)&Bt[(size_t)(bn + row) * DINNER + k0 + ch];
        }
        __syncthreads();
#pragma unroll
        for (int kk = 0; kk < 64; kk += 32) {
            s8v a = *(const s8v*)&As[(w * 16 + m) * PAD + kk + q * 8];
#pragma unroll
            for (int ct = 0; ct < 4; ++ct) {
                s8v b = *(const s8v*)&Bs[(ct * 16 + m) * PAD + kk + q * 8];
                acc[ct] = MFMA(a, b, acc[ct]);
            }
        }
    }
#pragma unroll
    for (int ct = 0; ct < 4; ++ct)
#pragma unroll
        for (int r = 0; r < 4; ++r)
            C[(size_t)(bm + w * 16 + q * 4 + r) * DIM + bn + ct * 16 + m] = acc[ct][r];
}

extern "C" void kernel_launch(void* const* d_in, const int* in_sizes, int n_in,
                              void* d_out, int out_size, void* d_ws, size_t ws_size,
                              hipStream_t stream) {
    const float* x     = (const float*)d_in[0];
    const float* gamma = (const float*)d_in[1];
    const float* w_qkv = (const float*)d_in[2];
    const float* w_out = (const float*)d_in[3];
    float* out = (float*)d_out;

    // normed hi/lo live in d_out (exact fit; consumed by gemm_qkv before partials overwrite)
    u16* nh = (u16*)d_out;
    u16* nl = nh + (size_t)SEQ * DIM;

    u16* p = (u16*)d_ws;
    u16* wqt_h = p; p += (size_t)QKVW * DIM;
    u16* wqt_l = p; p += (size_t)QKVW * DIM;
    u16* wot   = p; p += (size_t)DIM * DINNER;
    u16* qh = p; p += (size_t)SEQ * DINNER;
    u16* ql = p; p += (size_t)SEQ * DINNER;
    u16* kh = p; p += (size_t)SEQ * DINNER;
    u16* kl = p; p += (size_t)SEQ * DINNER;
    u16* vt = p; p += (size_t)DINNER * SEQ;
    u16* atto = p; p += (size_t)SEQ * DINNER;

    // split-KV partials: 1280 chunk-tiles x 16KB fp32. Tiles 0..1023 in d_out (16.78MB),
    // 1024..1279 in the dead wqt_h/wqt_l region. ml in ws.
    float* po_dout = (float*)d_out;
    float* po_wqt  = (float*)wqt_h;
    float* ml      = (float*)p;
    const size_t need = (size_t)((char*)(ml + (size_t)1280 * 128) - (char*)d_ws);  // ~32 MB
    const bool split = ws_size >= need;

    transpose_split<<<dim3(QKVW / 64, DIM / 64), 256, 0, stream>>>(w_qkv, wqt_h, wqt_l,
                                                                   DIM, QKVW, 1);
    transpose_split<<<dim3(DIM / 64, DINNER / 64), 256, 0, stream>>>(w_out, wot, nullptr,
                                                                     DINNER, DIM, 0);
    rmsnorm_split<<<SEQ, 256, 0, stream>>>(x, gamma, nh, nl);
    gemm_qkv_128<<<dim3(QKVW / 64, SEQ / 128), 256, 0, stream>>>(nh, nl, wqt_h, wqt_l,
                                                                 qh, ql, kh, kl, vt);
    if (split) {
        attn_chunk<<<dim3(256, HEADS), 256, 0, stream>>>(qh, ql, kh, kl, vt,
                                                         po_dout, po_wqt, ml);
        attn_merge<<<dim3(SEQ / 64, HEADS), 256, 0, stream>>>(po_dout, po_wqt, ml, atto);
    } else {
        attn_mfma<<<dim3(SEQ / 64, HEADS), 256, 0, stream>>>(qh, ql, kh, kl, vt, atto);
    }
    gemm_out_bf16<<<dim3(DIM / 64, SEQ / 64), 256, 0, stream>>>(atto, wot, out);
}

// Round 8
// 289.237 us; speedup vs baseline: 1.1464x; 1.0163x over previous
//
#include <hip/hip_runtime.h>
#include <math.h>

#define SEQ 4096
#define DIM 1024
#define HEADS 8
#define DINNER 512
#define QKVW 1536
#define PAD 80   // LDS row stride (bf16 elems) for legacy fallback kernels
#define CHUNK 16 // K-tiles (of 64) per split-KV chunk

typedef unsigned short u16;
typedef __attribute__((ext_vector_type(8))) short s8v;   // 8 bf16 (4 VGPRs)
typedef __attribute__((ext_vector_type(4))) float f4v;   // 4 fp32 acc
#define MFMA(a, b, c) __builtin_amdgcn_mfma_f32_16x16x32_bf16(a, b, c, 0, 0, 0)

__device__ __forceinline__ u16 f2bf(float f) {
    unsigned u = __float_as_uint(f);
    u += 0x7fff + ((u >> 16) & 1);   // RNE
    return (u16)(u >> 16);
}
__device__ __forceinline__ float bf2f(u16 b) { return __uint_as_float(((unsigned)b) << 16); }

// async global->LDS, 16B per lane. LDS dest is wave-uniform base + lane*16 (HW rule);
// the GLOBAL source is per-lane and pre-swizzled to realize the LDS XOR swizzle (rule #21).
__device__ __forceinline__ void gload16(const u16* g, u16* l) {
    __builtin_amdgcn_global_load_lds(
        (const __attribute__((address_space(1))) unsigned int*)g,
        (__attribute__((address_space(3))) unsigned int*)l, 16, 0, 0);
}

// chunk-tile flat index: T = h*160 + base16(qt) + c; nc(qt) = qt/16 + 1
__device__ __forceinline__ int base16(int qt) {
    int a = qt >> 4, b = qt & 15;
    return 8 * a * (a + 1) + b * (a + 1);
}
// partials: tiles 0..1023 in d_out, 1024..1279 in the dead wqt region
__device__ __forceinline__ float* po_sel(int T, float* pd, float* pw) {
    return (T < 1024) ? pd + (size_t)T * 4096 : pw + (size_t)(T - 1024) * 4096;
}

// ---------- RMSNorm -> split bf16 (hi, lo), vectorized (G13) ----------
__global__ __launch_bounds__(256) void rmsnorm_split(const float* __restrict__ x,
                                                     const float* __restrict__ gamma,
                                                     u16* __restrict__ hi,
                                                     u16* __restrict__ lo) {
    __shared__ float red[4];
    const int row = blockIdx.x, t = threadIdx.x;
    const float4 xv = ((const float4*)(x + (size_t)row * DIM))[t];
    float ss = xv.x * xv.x + xv.y * xv.y + xv.z * xv.z + xv.w * xv.w;
#pragma unroll
    for (int off = 32; off >= 1; off >>= 1) ss += __shfl_xor(ss, off, 64);
    if ((t & 63) == 0) red[t >> 6] = ss;
    __syncthreads();
    float scale = 32.0f / fmaxf(sqrtf(red[0] + red[1] + red[2] + red[3]), 1e-12f);
    const float4 gv = ((const float4*)gamma)[t];
    float y[4] = {xv.x * scale * gv.x, xv.y * scale * gv.y,
                  xv.z * scale * gv.z, xv.w * scale * gv.w};
    unsigned hw0, hw1, lw0, lw1;
    {
        u16 h0 = f2bf(y[0]), h1 = f2bf(y[1]), h2 = f2bf(y[2]), h3 = f2bf(y[3]);
        hw0 = (unsigned)h0 | ((unsigned)h1 << 16);
        hw1 = (unsigned)h2 | ((unsigned)h3 << 16);
        lw0 = (unsigned)f2bf(y[0] - bf2f(h0)) | ((unsigned)f2bf(y[1] - bf2f(h1)) << 16);
        lw1 = (unsigned)f2bf(y[2] - bf2f(h2)) | ((unsigned)f2bf(y[3] - bf2f(h3)) << 16);
    }
    *(uint2*)&hi[(size_t)row * DIM + t * 4] = make_uint2(hw0, hw1);
    *(uint2*)&lo[(size_t)row * DIM + t * 4] = make_uint2(lw0, lw1);
}

// ---------- transpose fp32 [R][C] -> bf16 hi/lo [C][R] ----------
__global__ __launch_bounds__(256) void transpose_split(const float* __restrict__ in,
                                                       u16* __restrict__ hi,
                                                       u16* __restrict__ lo,
                                                       int R, int C, int want_lo) {
    __shared__ float tile[64][65];
    const int c0 = blockIdx.x * 64, r0 = blockIdx.y * 64;
    const int t = threadIdx.x, col = t & 63, rb = t >> 6;
#pragma unroll
    for (int j = 0; j < 16; ++j)
        tile[rb + j * 4][col] = in[(size_t)(r0 + rb + j * 4) * C + c0 + col];
    __syncthreads();
#pragma unroll
    for (int j = 0; j < 16; ++j) {
        int cc = rb + j * 4;
        float v = tile[col][cc];
        size_t oi = (size_t)(c0 + cc) * R + r0 + col;
        u16 h = f2bf(v);
        hi[oi] = h;
        if (want_lo) lo[oi] = f2bf(v - bf2f(h));
    }
}

// ---------- QKV GEMM: 128x64 tile, global_load_lds staging, XOR-swizzled LDS ----------
__global__ __launch_bounds__(256) void gemm_qkv_128(
    const u16* __restrict__ Ah, const u16* __restrict__ Al,
    const u16* __restrict__ Bh, const u16* __restrict__ Bl,
    u16* __restrict__ qh, u16* __restrict__ ql,
    u16* __restrict__ kh, u16* __restrict__ kl, u16* __restrict__ vtp) {
    __shared__ __align__(16) u16 AsH[128 * 64], AsL[128 * 64];
    __shared__ __align__(16) u16 BsH[64 * 64], BsL[64 * 64];
    const int t = threadIdx.x;
    const int bn = blockIdx.x * 64, bm = blockIdx.y * 128;
    const int w = t >> 6, lane = t & 63, m = lane & 15, q = lane >> 4;
    const int wr = w >> 1, wc = w & 1;
    f4v acc[4][2];
#pragma unroll
    for (int i = 0; i < 4; ++i)
#pragma unroll
        for (int j = 0; j < 2; ++j) acc[i][j] = (f4v){0.f, 0.f, 0.f, 0.f};

    for (int k0 = 0; k0 < DIM; k0 += 64) {
        __syncthreads();
#pragma unroll
        for (int i = 0; i < 4; ++i) {
            int idx0 = i * 256 + w * 64;              // wave-uniform LDS granule base
            int row = (idx0 + lane) >> 3;
            int col = ((lane & 7) * 8) ^ ((row & 7) * 8);   // pre-swizzled source column
            gload16(&Ah[(size_t)(bm + row) * DIM + k0 + col], &AsH[idx0 * 8]);
            gload16(&Al[(size_t)(bm + row) * DIM + k0 + col], &AsL[idx0 * 8]);
            if (i < 2) {
                gload16(&Bh[(size_t)(bn + row) * DIM + k0 + col], &BsH[idx0 * 8]);
                gload16(&Bl[(size_t)(bn + row) * DIM + k0 + col], &BsL[idx0 * 8]);
            }
        }
        __syncthreads();   // compiler drains vmcnt(0) here
#pragma unroll
        for (int kk = 0; kk < 64; kk += 32) {
            s8v a_h[4], a_l[4], b_h[2], b_l[2];
#pragma unroll
            for (int f = 0; f < 4; ++f) {
                int ar = wr * 64 + f * 16 + m;
                int ab = ar * 128 + (((kk + q * 8) * 2) ^ ((ar & 7) << 4));
                a_h[f] = *(const s8v*)((const char*)AsH + ab);
                a_l[f] = *(const s8v*)((const char*)AsL + ab);
            }
#pragma unroll
            for (int f = 0; f < 2; ++f) {
                int br = wc * 32 + f * 16 + m;
                int bb = br * 128 + (((kk + q * 8) * 2) ^ ((br & 7) << 4));
                b_h[f] = *(const s8v*)((const char*)BsH + bb);
                b_l[f] = *(const s8v*)((const char*)BsL + bb);
            }
#pragma unroll
            for (int fm = 0; fm < 4; ++fm)
#pragma unroll
                for (int fn = 0; fn < 2; ++fn) {
                    acc[fm][fn] = MFMA(a_h[fm], b_h[fn], acc[fm][fn]);
                    acc[fm][fn] = MFMA(a_l[fm], b_h[fn], acc[fm][fn]);
                    acc[fm][fn] = MFMA(a_h[fm], b_l[fn], acc[fm][fn]);
                }
        }
    }
    const int region = bn >> 9;   // uniform per block
#pragma unroll
    for (int fm = 0; fm < 4; ++fm)
#pragma unroll
        for (int fn = 0; fn < 2; ++fn)
#pragma unroll
            for (int r = 0; r < 4; ++r) {
                int gr = bm + wr * 64 + fm * 16 + q * 4 + r;
                int gc = bn + wc * 32 + fn * 16 + m;
                float v = acc[fm][fn][r];
                if (region == 0) {
                    v *= 8.0f;   // q * sqrt(d), faithful to reference
                    u16 h = f2bf(v);
                    qh[(size_t)gr * DINNER + gc] = h;
                    ql[(size_t)gr * DINNER + gc] = f2bf(v - bf2f(h));
                } else if (region == 1) {
                    u16 h = f2bf(v);
                    kh[(size_t)gr * DINNER + (gc - 512)] = h;
                    kl[(size_t)gr * DINNER + (gc - 512)] = f2bf(v - bf2f(h));
                } else {
                    vtp[(size_t)(gc - 1024) * SEQ + gr] = f2bf(v);
                }
            }
}

// ---------- split-KV flash attention, swapped QK^T, 2-phase double-buffered staging ----------
// R5-verified version (115 us, conflicts 1.06M). The R6 counted-vmcnt variant failed the
// harness twice (suspected HW hang crossing raw s_barrier with in-flight global_load_lds
// in this structure) -- do NOT resubmit it unmodified.
__global__ __launch_bounds__(256) void attn_chunk(
    const u16* __restrict__ qhp, const u16* __restrict__ qlp,
    const u16* __restrict__ kh, const u16* __restrict__ kl,
    const u16* __restrict__ vt,
    float* __restrict__ po_dout, float* __restrict__ po_wqt,
    float* __restrict__ ml) {
    __shared__ __align__(16) u16 KH[2][64 * 64], KL[2][64 * 64], VT[2][64 * 64];
    const int t = threadIdx.x;
    const int bx = blockIdx.x;
    const int qt = 63 - (bx >> 2), c = bx & 3, h = blockIdx.y;
    if (c * CHUNK > qt) return;
    const int kt0 = c * CHUNK;
    const int kt1 = (qt < kt0 + CHUNK - 1) ? qt : (kt0 + CHUNK - 1);
    const int w = t >> 6, lane = t & 63, m = lane & 15, g = lane >> 4;

    // Q fragments in registers: row = qt*64 + w*16 + m, d-cols g*8 (+0 / +32)
    const size_t qrow = (size_t)(qt * 64 + w * 16 + m) * DINNER + h * 64;
    const s8v qf_h0 = *(const s8v*)&qhp[qrow + g * 8];
    const s8v qf_h1 = *(const s8v*)&qhp[qrow + 32 + g * 8];
    const s8v qf_l0 = *(const s8v*)&qlp[qrow + g * 8];
    const s8v qf_l1 = *(const s8v*)&qlp[qrow + 32 + g * 8];

    // staging: 512 granules (16B) per 8KB tile = 2 gload16 per thread per array
    const int sg0a = w * 64, sg0b = 256 + w * 64;
    const int srowa = (sg0a + lane) >> 3, srowb = (sg0b + lane) >> 3;
    const int sca = ((lane & 7) ^ (srowa & 7)) * 8;   // pre-swizzled source col (elems)
    const int scb = ((lane & 7) ^ (srowb & 7)) * 8;

    f4v o[4] = {{0.f, 0.f, 0.f, 0.f}, {0.f, 0.f, 0.f, 0.f},
                {0.f, 0.f, 0.f, 0.f}, {0.f, 0.f, 0.f, 0.f}};
    float mi_s = -1e30f, li_s = 0.f;   // per-lane stats for q = w*16 + m

    // prologue: stage first tile into buf 0
    {
        const u16* kr = &kh[(size_t)(kt0 * 64) * DINNER + h * 64];
        const u16* lr = &kl[(size_t)(kt0 * 64) * DINNER + h * 64];
        const u16* vr = &vt[(size_t)(h * 64) * SEQ + kt0 * 64];
        gload16(kr + (size_t)srowa * DINNER + sca, &KH[0][sg0a * 8]);
        gload16(kr + (size_t)srowb * DINNER + scb, &KH[0][sg0b * 8]);
        gload16(lr + (size_t)srowa * DINNER + sca, &KL[0][sg0a * 8]);
        gload16(lr + (size_t)srowb * DINNER + scb, &KL[0][sg0b * 8]);
        gload16(vr + (size_t)srowa * SEQ + sca, &VT[0][sg0a * 8]);
        gload16(vr + (size_t)srowb * SEQ + scb, &VT[0][sg0b * 8]);
    }
    __syncthreads();   // drains vmcnt(0)

    int cur = 0;
    for (int kt = kt0; kt <= kt1; ++kt) {
        if (kt < kt1) {   // prefetch next tile into buf^1; hides under QK+softmax
            int nb = cur ^ 1;
            const u16* kr = &kh[(size_t)((kt + 1) * 64) * DINNER + h * 64];
            const u16* lr = &kl[(size_t)((kt + 1) * 64) * DINNER + h * 64];
            const u16* vr = &vt[(size_t)(h * 64) * SEQ + (kt + 1) * 64];
            gload16(kr + (size_t)srowa * DINNER + sca, &KH[nb][sg0a * 8]);
            gload16(kr + (size_t)srowb * DINNER + scb, &KH[nb][sg0b * 8]);
            gload16(lr + (size_t)srowa * DINNER + sca, &KL[nb][sg0a * 8]);
            gload16(lr + (size_t)srowb * DINNER + scb, &KL[nb][sg0b * 8]);
            gload16(vr + (size_t)srowa * SEQ + sca, &VT[nb][sg0a * 8]);
            gload16(vr + (size_t)srowb * SEQ + scb, &VT[nb][sg0b * 8]);
        }

        // S^T: s[ct][r] = S[q=w*16+m][kv=ct*16+g*4+r]; 3 MFMAs per 16x16x32 (split bf16)
        const char* KHc = (const char*)KH[cur];
        const char* KLc = (const char*)KL[cur];
        f4v s[4] = {{0.f, 0.f, 0.f, 0.f}, {0.f, 0.f, 0.f, 0.f},
                    {0.f, 0.f, 0.f, 0.f}, {0.f, 0.f, 0.f, 0.f}};
#pragma unroll
        for (int ct = 0; ct < 4; ++ct) {
            int rr = ct * 16 + m, rb = rr * 128, sw = (rr & 7) << 4;
            s8v bh0 = *(const s8v*)(KHc + rb + ((g * 16) ^ sw));
            s8v bl0 = *(const s8v*)(KLc + rb + ((g * 16) ^ sw));
            s[ct] = MFMA(bh0, qf_h0, s[ct]);
            s[ct] = MFMA(bh0, qf_l0, s[ct]);
            s[ct] = MFMA(bl0, qf_h0, s[ct]);
            s8v bh1 = *(const s8v*)(KHc + rb + ((64 + g * 16) ^ sw));
            s8v bl1 = *(const s8v*)(KLc + rb + ((64 + g * 16) ^ sw));
            s[ct] = MFMA(bh1, qf_h1, s[ct]);
            s[ct] = MFMA(bh1, qf_l1, s[ct]);
            s[ct] = MFMA(bl1, qf_h1, s[ct]);
        }
        if (kt == qt) {   // causal: mask kv > q (tile-local)
#pragma unroll
            for (int ct = 0; ct < 4; ++ct)
#pragma unroll
                for (int r = 0; r < 4; ++r)
                    if (ct * 16 + g * 4 + r > w * 16 + m) s[ct][r] = -1e30f;
        }

        // lane-local online softmax for q = w*16+m (16 kv values per lane)
        float rm = -1e30f;
#pragma unroll
        for (int ct = 0; ct < 4; ++ct)
#pragma unroll
            for (int r = 0; r < 4; ++r) rm = fmaxf(rm, s[ct][r]);
        rm = fmaxf(rm, __shfl_xor(rm, 16, 64));
        rm = fmaxf(rm, __shfl_xor(rm, 32, 64));
        float mn = fmaxf(mi_s, rm);
        float al = __expf(mi_s - mn);
        mi_s = mn;
        float rs = 0.f;
#pragma unroll
        for (int ct = 0; ct < 4; ++ct)
#pragma unroll
            for (int r = 0; r < 4; ++r) {
                s[ct][r] = __expf(s[ct][r] - mn);
                rs += s[ct][r];
            }
        rs += __shfl_xor(rs, 16, 64);
        rs += __shfl_xor(rs, 32, 64);
        li_s = li_s * al + rs;
        float alo[4];
#pragma unroll
        for (int r = 0; r < 4; ++r) alo[r] = __shfl(al, g * 4 + r, 64);

        __syncthreads();   // all waves done reading K[cur]; prefetch drains here

        // P -> KH[cur] (dead), swizzled; uint2 = 4 bf16 at linear col ct*16+g*4
        const int pr = w * 16 + m, pb = pr * 128, psw = (pr & 7) << 4;
#pragma unroll
        for (int ct = 0; ct < 4; ++ct) {
            unsigned w0 = (unsigned)f2bf(s[ct][0]) | ((unsigned)f2bf(s[ct][1]) << 16);
            unsigned w1 = (unsigned)f2bf(s[ct][2]) | ((unsigned)f2bf(s[ct][3]) << 16);
            *(uint2*)((char*)KH[cur] + pb + ((ct * 32 + g * 8) ^ psw)) = make_uint2(w0, w1);
        }
#pragma unroll
        for (int ct = 0; ct < 4; ++ct)
#pragma unroll
            for (int r = 0; r < 4; ++r) o[ct][r] *= alo[r];
        // PV: each wave reads only its own P rows -> no extra barrier
#pragma unroll
        for (int kk = 0; kk < 2; ++kk) {
            s8v ap = *(const s8v*)((const char*)KH[cur] + pb + ((kk * 64 + g * 16) ^ psw));
#pragma unroll
            for (int ct = 0; ct < 4; ++ct) {
                int vr2 = ct * 16 + m;
                s8v bv = *(const s8v*)((const char*)VT[cur] + vr2 * 128 +
                                       ((kk * 64 + g * 16) ^ ((vr2 & 7) << 4)));
                o[ct] = MFMA(ap, bv, o[ct]);
            }
        }
        __syncthreads();   // PV done across waves -> buf[cur] recyclable next iter
        cur ^= 1;
    }

    // epilogue: raw partial o (fp32) + per-row (m, l)
    const int T = h * 160 + base16(qt) + c;
    float* po = po_sel(T, po_dout, po_wqt);
#pragma unroll
    for (int ct = 0; ct < 4; ++ct)
#pragma unroll
        for (int r = 0; r < 4; ++r)
            po[(size_t)(w * 16 + g * 4 + r) * 64 + ct * 16 + m] = o[ct][r];
    if (g == 0) {
        ml[(size_t)T * 128 + w * 16 + m] = mi_s;
        ml[(size_t)T * 128 + 64 + w * 16 + m] = li_s;
    }
}

// ---------- merge split-KV partials -> atto bf16 ----------
__global__ __launch_bounds__(256) void attn_merge(
    float* __restrict__ po_dout, float* __restrict__ po_wqt,
    const float* __restrict__ ml, u16* __restrict__ atto) {
    const int qt = blockIdx.x, h = blockIdx.y;
    const int nc = (qt >> 4) + 1;
    const int t = threadIdx.x, col = t & 63, rg = t >> 6;
    const int T0 = h * 160 + base16(qt);
    for (int j = 0; j < 16; ++j) {
        int row = rg * 16 + j;
        float mv[4], lv[4], M = -1e30f;
#pragma unroll 4
        for (int cc = 0; cc < 4; ++cc)
            if (cc < nc) {
                mv[cc] = ml[(size_t)(T0 + cc) * 128 + row];
                lv[cc] = ml[(size_t)(T0 + cc) * 128 + 64 + row];
                M = fmaxf(M, mv[cc]);
            }
        float acc = 0.f, den = 0.f;
#pragma unroll 4
        for (int cc = 0; cc < 4; ++cc)
            if (cc < nc) {
                const float* po = po_sel(T0 + cc, po_dout, po_wqt);
                float wg = __expf(mv[cc] - M);
                den += lv[cc] * wg;
                acc += wg * po[(size_t)row * 64 + col];
            }
        atto[(size_t)(qt * 64 + row) * DINNER + h * 64 + col] = f2bf(acc / den);
    }
}

// ---------- fallback: original fused flash attention (used if workspace too small) ----------
__global__ __launch_bounds__(256) void attn_mfma(
    const u16* __restrict__ qh, const u16* __restrict__ ql,
    const u16* __restrict__ kh, const u16* __restrict__ kl,
    const u16* __restrict__ vt, u16* __restrict__ atto) {
    __shared__ u16 Qh[64 * PAD], Ql[64 * PAD], KP[64 * PAD], Kl[64 * PAD], Vt[64 * PAD];
    const int t = threadIdx.x;
    const int qt = blockIdx.x, h = blockIdx.y;
    const int w = t >> 6, lane = t & 63, m = lane & 15, q = lane >> 4;

#pragma unroll
    for (int i = 0; i < 2; ++i) {
        int c = t + i * 256, row = c >> 3, ch = (c & 7) * 8;
        *(uint4*)&Qh[row * PAD + ch] =
            *(const uint4*)&qh[(size_t)(qt * 64 + row) * DINNER + h * 64 + ch];
        *(uint4*)&Ql[row * PAD + ch] =
            *(const uint4*)&ql[(size_t)(qt * 64 + row) * DINNER + h * 64 + ch];
    }

    f4v o[4] = {{0.f, 0.f, 0.f, 0.f}, {0.f, 0.f, 0.f, 0.f},
                {0.f, 0.f, 0.f, 0.f}, {0.f, 0.f, 0.f, 0.f}};
    float mi[4] = {-1e30f, -1e30f, -1e30f, -1e30f};
    float li[4] = {0.f, 0.f, 0.f, 0.f};

    for (int kt = 0; kt <= qt; ++kt) {
        __syncthreads();
#pragma unroll
        for (int i = 0; i < 2; ++i) {
            int c = t + i * 256, row = c >> 3, ch = (c & 7) * 8;
            *(uint4*)&KP[row * PAD + ch] =
                *(const uint4*)&kh[(size_t)(kt * 64 + row) * DINNER + h * 64 + ch];
            *(uint4*)&Kl[row * PAD + ch] =
                *(const uint4*)&kl[(size_t)(kt * 64 + row) * DINNER + h * 64 + ch];
            *(uint4*)&Vt[row * PAD + ch] =
                *(const uint4*)&vt[(size_t)(h * 64 + row) * SEQ + kt * 64 + ch];
        }
        __syncthreads();

        f4v s[4] = {{0.f, 0.f, 0.f, 0.f}, {0.f, 0.f, 0.f, 0.f},
                    {0.f, 0.f, 0.f, 0.f}, {0.f, 0.f, 0.f, 0.f}};
#pragma unroll
        for (int kk = 0; kk < 64; kk += 32) {
            s8v ah = *(const s8v*)&Qh[(w * 16 + m) * PAD + kk + q * 8];
            s8v al = *(const s8v*)&Ql[(w * 16 + m) * PAD + kk + q * 8];
#pragma unroll
            for (int ct = 0; ct < 4; ++ct) {
                s8v bh = *(const s8v*)&KP[(ct * 16 + m) * PAD + kk + q * 8];
                s8v bl = *(const s8v*)&Kl[(ct * 16 + m) * PAD + kk + q * 8];
                s[ct] = MFMA(ah, bh, s[ct]);
                s[ct] = MFMA(al, bh, s[ct]);
                s[ct] = MFMA(ah, bl, s[ct]);
            }
        }
        if (kt == qt) {
#pragma unroll
            for (int ct = 0; ct < 4; ++ct)
#pragma unroll
                for (int r = 0; r < 4; ++r)
                    if (ct * 16 + m > w * 16 + q * 4 + r) s[ct][r] = -1e30f;
        }

        float alpha[4];
#pragma unroll
        for (int r = 0; r < 4; ++r) {
            float rm = fmaxf(fmaxf(s[0][r], s[1][r]), fmaxf(s[2][r], s[3][r]));
#pragma unroll
            for (int off = 8; off >= 1; off >>= 1) rm = fmaxf(rm, __shfl_xor(rm, off, 64));
            float mn = fmaxf(mi[r], rm);
            alpha[r] = __expf(mi[r] - mn);
            mi[r] = mn;
            float rs = 0.f;
#pragma unroll
            for (int ct = 0; ct < 4; ++ct) {
                s[ct][r] = __expf(s[ct][r] - mn);
                rs += s[ct][r];
            }
#pragma unroll
            for (int off = 8; off >= 1; off >>= 1) rs += __shfl_xor(rs, off, 64);
            li[r] = li[r] * alpha[r] + rs;
        }

        __syncthreads();
#pragma unroll
        for (int ct = 0; ct < 4; ++ct)
#pragma unroll
            for (int r = 0; r < 4; ++r) {
                KP[(w * 16 + q * 4 + r) * PAD + ct * 16 + m] = f2bf(s[ct][r]);
                o[ct][r] *= alpha[r];
            }
#pragma unroll
        for (int kk = 0; kk < 64; kk += 32) {
            s8v ap = *(const s8v*)&KP[(w * 16 + m) * PAD + kk + q * 8];
#pragma unroll
            for (int ct = 0; ct < 4; ++ct) {
                s8v bv = *(const s8v*)&Vt[(ct * 16 + m) * PAD + kk + q * 8];
                o[ct] = MFMA(ap, bv, o[ct]);
            }
        }
    }

#pragma unroll
    for (int r = 0; r < 4; ++r) {
        float inv = 1.0f / li[r];
#pragma unroll
        for (int ct = 0; ct < 4; ++ct)
            atto[(size_t)(qt * 64 + w * 16 + q * 4 + r) * DINNER + h * 64 + ct * 16 + m] =
                f2bf(o[ct][r] * inv);
    }
}

// ---------- out projection: 128x64 tile, global_load_lds + XOR swizzle ----------
// atto bf16 [4096][512] @ w_out^T bf16 [1024][512] -> fp32 C [4096][1024].
// Line-for-line adaptation of the verified gemm_qkv_128 structure, single-precision path.
__global__ __launch_bounds__(256) void gemm_out_128(const u16* __restrict__ A,
                                                    const u16* __restrict__ Bt,
                                                    float* __restrict__ C) {
    __shared__ __align__(16) u16 As[128 * 64], Bs[64 * 64];
    const int t = threadIdx.x;
    const int bn = blockIdx.x * 64, bm = blockIdx.y * 128;
    const int w = t >> 6, lane = t & 63, m = lane & 15, q = lane >> 4;
    const int wr = w >> 1, wc = w & 1;
    f4v acc[4][2];
#pragma unroll
    for (int i = 0; i < 4; ++i)
#pragma unroll
        for (int j = 0; j < 2; ++j) acc[i][j] = (f4v){0.f, 0.f, 0.f, 0.f};

    for (int k0 = 0; k0 < DINNER; k0 += 64) {
        __syncthreads();
#pragma unroll
        for (int i = 0; i < 4; ++i) {
            int idx0 = i * 256 + w * 64;
            int row = (idx0 + lane) >> 3;
            int col = ((lane & 7) * 8) ^ ((row & 7) * 8);
            gload16(&A[(size_t)(bm + row) * DINNER + k0 + col], &As[idx0 * 8]);
            if (i < 2)
                gload16(&Bt[(size_t)(bn + row) * DINNER + k0 + col], &Bs[idx0 * 8]);
        }
        __syncthreads();
#pragma unroll
        for (int kk = 0; kk < 64; kk += 32) {
            s8v a_f[4], b_f[2];
#pragma unroll
            for (int f = 0; f < 4; ++f) {
                int ar = wr * 64 + f * 16 + m;
                a_f[f] = *(const s8v*)((const char*)As + ar * 128 +
                                       (((kk + q * 8) * 2) ^ ((ar & 7) << 4)));
            }
#pragma unroll
            for (int f = 0; f < 2; ++f) {
                int br = wc * 32 + f * 16 + m;
                b_f[f] = *(const s8v*)((const char*)Bs + br * 128 +
                                       (((kk + q * 8) * 2) ^ ((br & 7) << 4)));
            }
#pragma unroll
            for (int fm = 0; fm < 4; ++fm)
#pragma unroll
                for (int fn = 0; fn < 2; ++fn)
                    acc[fm][fn] = MFMA(a_f[fm], b_f[fn], acc[fm][fn]);
        }
    }
#pragma unroll
    for (int fm = 0; fm < 4; ++fm)
#pragma unroll
        for (int fn = 0; fn < 2; ++fn)
#pragma unroll
            for (int r = 0; r < 4; ++r)
                C[(size_t)(bm + wr * 64 + fm * 16 + q * 4 + r) * DIM +
                  bn + wc * 32 + fn * 16 + m] = acc[fm][fn][r];
}

extern "C" void kernel_launch(void* const* d_in, const int* in_sizes, int n_in,
                              void* d_out, int out_size, void* d_ws, size_t ws_size,
                              hipStream_t stream) {
    const float* x     = (const float*)d_in[0];
    const float* gamma = (const float*)d_in[1];
    const float* w_qkv = (const float*)d_in[2];
    const float* w_out = (const float*)d_in[3];
    float* out = (float*)d_out;

    // normed hi/lo live in d_out (exact fit; consumed by gemm_qkv before partials overwrite)
    u16* nh = (u16*)d_out;
    u16* nl = nh + (size_t)SEQ * DIM;

    u16* p = (u16*)d_ws;
    u16* wqt_h = p; p += (size_t)QKVW * DIM;
    u16* wqt_l = p; p += (size_t)QKVW * DIM;
    u16* wot   = p; p += (size_t)DIM * DINNER;
    u16* qh = p; p += (size_t)SEQ * DINNER;
    u16* ql = p; p += (size_t)SEQ * DINNER;
    u16* kh = p; p += (size_t)SEQ * DINNER;
    u16* kl = p; p += (size_t)SEQ * DINNER;
    u16* vt = p; p += (size_t)DINNER * SEQ;
    u16* atto = p; p += (size_t)SEQ * DINNER;

    // split-KV partials: 1280 chunk-tiles x 16KB fp32. Tiles 0..1023 in d_out (16.78MB),
    // 1024..1279 in the dead wqt_h/wqt_l region. ml in ws.
    float* po_dout = (float*)d_out;
    float* po_wqt  = (float*)wqt_h;
    float* ml      = (float*)p;
    const size_t need = (size_t)((char*)(ml + (size_t)1280 * 128) - (char*)d_ws);  // ~32 MB
    const bool split = ws_size >= need;

    transpose_split<<<dim3(QKVW / 64, DIM / 64), 256, 0, stream>>>(w_qkv, wqt_h, wqt_l,
                                                                   DIM, QKVW, 1);
    transpose_split<<<dim3(DIM / 64, DINNER / 64), 256, 0, stream>>>(w_out, wot, nullptr,
                                                                     DINNER, DIM, 0);
    rmsnorm_split<<<SEQ, 256, 0, stream>>>(x, gamma, nh, nl);
    gemm_qkv_128<<<dim3(QKVW / 64, SEQ / 128), 256, 0, stream>>>(nh, nl, wqt_h, wqt_l,
                                                                 qh, ql, kh, kl, vt);
    if (split) {
        attn_chunk<<<dim3(256, HEADS), 256, 0, stream>>>(qh, ql, kh, kl, vt,
                                                         po_dout, po_wqt, ml);
        attn_merge<<<dim3(SEQ / 64, HEADS), 256, 0, stream>>>(po_dout, po_wqt, ml, atto);
    } else {
        attn_mfma<<<dim3(SEQ / 64, HEADS), 256, 0, stream>>>(qh, ql, kh, kl, vt, atto);
    }
    gemm_out_128<<<dim3(DIM / 64, SEQ / 128), 256, 0, stream>>>(atto, wot, out);
}

// Round 9
// 281.315 us; speedup vs baseline: 1.1787x; 1.0282x over previous
//
#include <hip/hip_runtime.h>
#include <math.h>

#define SEQ 4096
#define DIM 1024
#define HEADS 8
#define DINNER 512
#define QKVW 1536
#define PAD 80   // LDS row stride (bf16 elems) for legacy fallback kernels
#define CHUNK 16 // K-tiles (of 64) per split-KV chunk

typedef unsigned short u16;
typedef __attribute__((ext_vector_type(8))) short s8v;   // 8 bf16 (4 VGPRs)
typedef __attribute__((ext_vector_type(4))) float f4v;   // 4 fp32 acc
#define MFMA(a, b, c) __builtin_amdgcn_mfma_f32_16x16x32_bf16(a, b, c, 0, 0, 0)

__device__ __forceinline__ u16 f2bf(float f) {
    unsigned u = __float_as_uint(f);
    u += 0x7fff + ((u >> 16) & 1);   // RNE
    return (u16)(u >> 16);
}
__device__ __forceinline__ float bf2f(u16 b) { return __uint_as_float(((unsigned)b) << 16); }

// async global->LDS, 16B per lane. LDS dest is wave-uniform base + lane*16 (HW rule);
// the GLOBAL source is per-lane and pre-swizzled to realize the LDS XOR swizzle (rule #21).
__device__ __forceinline__ void gload16(const u16* g, u16* l) {
    __builtin_amdgcn_global_load_lds(
        (const __attribute__((address_space(1))) unsigned int*)g,
        (__attribute__((address_space(3))) unsigned int*)l, 16, 0, 0);
}

// chunk-tile flat index: T = h*160 + base16(qt) + c; nc(qt) = qt/16 + 1
__device__ __forceinline__ int base16(int qt) {
    int a = qt >> 4, b = qt & 15;
    return 8 * a * (a + 1) + b * (a + 1);
}
// partials: tiles 0..1023 in d_out, 1024..1279 in the dead wqt region
__device__ __forceinline__ float* po_sel(int T, float* pd, float* pw) {
    return (T < 1024) ? pd + (size_t)T * 4096 : pw + (size_t)(T - 1024) * 4096;
}

// ---------- RMSNorm -> split bf16 (hi, lo), vectorized (G13) ----------
__global__ __launch_bounds__(256) void rmsnorm_split(const float* __restrict__ x,
                                                     const float* __restrict__ gamma,
                                                     u16* __restrict__ hi,
                                                     u16* __restrict__ lo) {
    __shared__ float red[4];
    const int row = blockIdx.x, t = threadIdx.x;
    const float4 xv = ((const float4*)(x + (size_t)row * DIM))[t];
    float ss = xv.x * xv.x + xv.y * xv.y + xv.z * xv.z + xv.w * xv.w;
#pragma unroll
    for (int off = 32; off >= 1; off >>= 1) ss += __shfl_xor(ss, off, 64);
    if ((t & 63) == 0) red[t >> 6] = ss;
    __syncthreads();
    float scale = 32.0f / fmaxf(sqrtf(red[0] + red[1] + red[2] + red[3]), 1e-12f);
    const float4 gv = ((const float4*)gamma)[t];
    float y[4] = {xv.x * scale * gv.x, xv.y * scale * gv.y,
                  xv.z * scale * gv.z, xv.w * scale * gv.w};
    unsigned hw0, hw1, lw0, lw1;
    {
        u16 h0 = f2bf(y[0]), h1 = f2bf(y[1]), h2 = f2bf(y[2]), h3 = f2bf(y[3]);
        hw0 = (unsigned)h0 | ((unsigned)h1 << 16);
        hw1 = (unsigned)h2 | ((unsigned)h3 << 16);
        lw0 = (unsigned)f2bf(y[0] - bf2f(h0)) | ((unsigned)f2bf(y[1] - bf2f(h1)) << 16);
        lw1 = (unsigned)f2bf(y[2] - bf2f(h2)) | ((unsigned)f2bf(y[3] - bf2f(h3)) << 16);
    }
    *(uint2*)&hi[(size_t)row * DIM + t * 4] = make_uint2(hw0, hw1);
    *(uint2*)&lo[(size_t)row * DIM + t * 4] = make_uint2(lw0, lw1);
}

// ---------- transpose fp32 [R][C] -> bf16 hi/lo [C][R] ----------
__global__ __launch_bounds__(256) void transpose_split(const float* __restrict__ in,
                                                       u16* __restrict__ hi,
                                                       u16* __restrict__ lo,
                                                       int R, int C, int want_lo) {
    __shared__ float tile[64][65];
    const int c0 = blockIdx.x * 64, r0 = blockIdx.y * 64;
    const int t = threadIdx.x, col = t & 63, rb = t >> 6;
#pragma unroll
    for (int j = 0; j < 16; ++j)
        tile[rb + j * 4][col] = in[(size_t)(r0 + rb + j * 4) * C + c0 + col];
    __syncthreads();
#pragma unroll
    for (int j = 0; j < 16; ++j) {
        int cc = rb + j * 4;
        float v = tile[col][cc];
        size_t oi = (size_t)(c0 + cc) * R + r0 + col;
        u16 h = f2bf(v);
        hi[oi] = h;
        if (want_lo) lo[oi] = f2bf(v - bf2f(h));
    }
}

// ---------- QKV GEMM: 128x64 tile, global_load_lds staging, XOR-swizzled LDS ----------
__global__ __launch_bounds__(256) void gemm_qkv_128(
    const u16* __restrict__ Ah, const u16* __restrict__ Al,
    const u16* __restrict__ Bh, const u16* __restrict__ Bl,
    u16* __restrict__ qh, u16* __restrict__ ql,
    u16* __restrict__ kh, u16* __restrict__ kl, u16* __restrict__ vtp) {
    __shared__ __align__(16) u16 AsH[128 * 64], AsL[128 * 64];
    __shared__ __align__(16) u16 BsH[64 * 64], BsL[64 * 64];
    const int t = threadIdx.x;
    const int bn = blockIdx.x * 64, bm = blockIdx.y * 128;
    const int w = t >> 6, lane = t & 63, m = lane & 15, q = lane >> 4;
    const int wr = w >> 1, wc = w & 1;
    f4v acc[4][2];
#pragma unroll
    for (int i = 0; i < 4; ++i)
#pragma unroll
        for (int j = 0; j < 2; ++j) acc[i][j] = (f4v){0.f, 0.f, 0.f, 0.f};

    for (int k0 = 0; k0 < DIM; k0 += 64) {
        __syncthreads();
#pragma unroll
        for (int i = 0; i < 4; ++i) {
            int idx0 = i * 256 + w * 64;              // wave-uniform LDS granule base
            int row = (idx0 + lane) >> 3;
            int col = ((lane & 7) * 8) ^ ((row & 7) * 8);   // pre-swizzled source column
            gload16(&Ah[(size_t)(bm + row) * DIM + k0 + col], &AsH[idx0 * 8]);
            gload16(&Al[(size_t)(bm + row) * DIM + k0 + col], &AsL[idx0 * 8]);
            if (i < 2) {
                gload16(&Bh[(size_t)(bn + row) * DIM + k0 + col], &BsH[idx0 * 8]);
                gload16(&Bl[(size_t)(bn + row) * DIM + k0 + col], &BsL[idx0 * 8]);
            }
        }
        __syncthreads();   // compiler drains vmcnt(0) here
#pragma unroll
        for (int kk = 0; kk < 64; kk += 32) {
            s8v a_h[4], a_l[4], b_h[2], b_l[2];
#pragma unroll
            for (int f = 0; f < 4; ++f) {
                int ar = wr * 64 + f * 16 + m;
                int ab = ar * 128 + (((kk + q * 8) * 2) ^ ((ar & 7) << 4));
                a_h[f] = *(const s8v*)((const char*)AsH + ab);
                a_l[f] = *(const s8v*)((const char*)AsL + ab);
            }
#pragma unroll
            for (int f = 0; f < 2; ++f) {
                int br = wc * 32 + f * 16 + m;
                int bb = br * 128 + (((kk + q * 8) * 2) ^ ((br & 7) << 4));
                b_h[f] = *(const s8v*)((const char*)BsH + bb);
                b_l[f] = *(const s8v*)((const char*)BsL + bb);
            }
#pragma unroll
            for (int fm = 0; fm < 4; ++fm)
#pragma unroll
                for (int fn = 0; fn < 2; ++fn) {
                    acc[fm][fn] = MFMA(a_h[fm], b_h[fn], acc[fm][fn]);
                    acc[fm][fn] = MFMA(a_l[fm], b_h[fn], acc[fm][fn]);
                    acc[fm][fn] = MFMA(a_h[fm], b_l[fn], acc[fm][fn]);
                }
        }
    }
    const int region = bn >> 9;   // uniform per block
#pragma unroll
    for (int fm = 0; fm < 4; ++fm)
#pragma unroll
        for (int fn = 0; fn < 2; ++fn)
#pragma unroll
            for (int r = 0; r < 4; ++r) {
                int gr = bm + wr * 64 + fm * 16 + q * 4 + r;
                int gc = bn + wc * 32 + fn * 16 + m;
                float v = acc[fm][fn][r];
                if (region == 0) {
                    v *= 8.0f;   // q * sqrt(d), faithful to reference
                    u16 h = f2bf(v);
                    qh[(size_t)gr * DINNER + gc] = h;
                    ql[(size_t)gr * DINNER + gc] = f2bf(v - bf2f(h));
                } else if (region == 1) {
                    u16 h = f2bf(v);
                    kh[(size_t)gr * DINNER + (gc - 512)] = h;
                    kl[(size_t)gr * DINNER + (gc - 512)] = f2bf(v - bf2f(h));
                } else {
                    vtp[(size_t)(gc - 1024) * SEQ + gr] = f2bf(v);
                }
            }
}

// ---------- split-KV flash attention: swapped QK^T, 2 Q-TILES PER BLOCK ----------
// Block (j, c) processes qtA=2j and qtB=2j+1 for chunk c: K/V staged ONCE per tile,
// consumed by two QK/softmax/PV passes -> staging+barrier overhead amortized 2x.
// (2j, 2j+1) have identical chunk membership; only kt==qtB (B diagonal) skips A
// (block-uniform). P_A -> KH[cur] (dead), P_B -> KL[cur] (dead). P packed to bf16
// PRE-barrier to cap VGPR. Sync structure identical to R5/R8-verified version.
__global__ __launch_bounds__(256) void attn_chunk(
    const u16* __restrict__ qhp, const u16* __restrict__ qlp,
    const u16* __restrict__ kh, const u16* __restrict__ kl,
    const u16* __restrict__ vt,
    float* __restrict__ po_dout, float* __restrict__ po_wqt,
    float* __restrict__ ml) {
    __shared__ __align__(16) u16 KH[2][64 * 64], KL[2][64 * 64], VT[2][64 * 64];
    const int t = threadIdx.x;
    const int bx = blockIdx.x;
    const int j = 31 - (bx >> 2), c = bx & 3, h = blockIdx.y;
    if (8 * c > j) return;
    const int qtA = 2 * j, qtB = 2 * j + 1;
    const int kt0 = c * CHUNK;
    const int kt1 = (qtB < kt0 + CHUNK - 1) ? qtB : (kt0 + CHUNK - 1);
    const int w = t >> 6, lane = t & 63, m = lane & 15, g = lane >> 4;

    // Q fragments in registers for both tiles: row = qt*64 + w*16 + m, d-cols g*8 (+0/+32)
    const size_t qrowA = (size_t)(qtA * 64 + w * 16 + m) * DINNER + h * 64;
    const size_t qrowB = (size_t)(qtB * 64 + w * 16 + m) * DINNER + h * 64;
    const s8v qA_h0 = *(const s8v*)&qhp[qrowA + g * 8];
    const s8v qA_h1 = *(const s8v*)&qhp[qrowA + 32 + g * 8];
    const s8v qA_l0 = *(const s8v*)&qlp[qrowA + g * 8];
    const s8v qA_l1 = *(const s8v*)&qlp[qrowA + 32 + g * 8];
    const s8v qB_h0 = *(const s8v*)&qhp[qrowB + g * 8];
    const s8v qB_h1 = *(const s8v*)&qhp[qrowB + 32 + g * 8];
    const s8v qB_l0 = *(const s8v*)&qlp[qrowB + g * 8];
    const s8v qB_l1 = *(const s8v*)&qlp[qrowB + 32 + g * 8];

    // staging: 512 granules (16B) per 8KB tile = 2 gload16 per thread per array
    const int sg0a = w * 64, sg0b = 256 + w * 64;
    const int srowa = (sg0a + lane) >> 3, srowb = (sg0b + lane) >> 3;
    const int sca = ((lane & 7) ^ (srowa & 7)) * 8;   // pre-swizzled source col (elems)
    const int scb = ((lane & 7) ^ (srowb & 7)) * 8;

    f4v oA[4] = {{0.f, 0.f, 0.f, 0.f}, {0.f, 0.f, 0.f, 0.f},
                 {0.f, 0.f, 0.f, 0.f}, {0.f, 0.f, 0.f, 0.f}};
    f4v oB[4] = {{0.f, 0.f, 0.f, 0.f}, {0.f, 0.f, 0.f, 0.f},
                 {0.f, 0.f, 0.f, 0.f}, {0.f, 0.f, 0.f, 0.f}};
    float miA = -1e30f, liA = 0.f, miB = -1e30f, liB = 0.f;

    // prologue: stage first tile into buf 0
    {
        const u16* kr = &kh[(size_t)(kt0 * 64) * DINNER + h * 64];
        const u16* lr = &kl[(size_t)(kt0 * 64) * DINNER + h * 64];
        const u16* vr = &vt[(size_t)(h * 64) * SEQ + kt0 * 64];
        gload16(kr + (size_t)srowa * DINNER + sca, &KH[0][sg0a * 8]);
        gload16(kr + (size_t)srowb * DINNER + scb, &KH[0][sg0b * 8]);
        gload16(lr + (size_t)srowa * DINNER + sca, &KL[0][sg0a * 8]);
        gload16(lr + (size_t)srowb * DINNER + scb, &KL[0][sg0b * 8]);
        gload16(vr + (size_t)srowa * SEQ + sca, &VT[0][sg0a * 8]);
        gload16(vr + (size_t)srowb * SEQ + scb, &VT[0][sg0b * 8]);
    }
    __syncthreads();   // drains vmcnt(0)

    int cur = 0;
    for (int kt = kt0; kt <= kt1; ++kt) {
        if (kt < kt1) {   // prefetch next tile into buf^1; drains at next mid-barrier
            int nb = cur ^ 1;
            const u16* kr = &kh[(size_t)((kt + 1) * 64) * DINNER + h * 64];
            const u16* lr = &kl[(size_t)((kt + 1) * 64) * DINNER + h * 64];
            const u16* vr = &vt[(size_t)(h * 64) * SEQ + (kt + 1) * 64];
            gload16(kr + (size_t)srowa * DINNER + sca, &KH[nb][sg0a * 8]);
            gload16(kr + (size_t)srowb * DINNER + scb, &KH[nb][sg0b * 8]);
            gload16(lr + (size_t)srowa * DINNER + sca, &KL[nb][sg0a * 8]);
            gload16(lr + (size_t)srowb * DINNER + scb, &KL[nb][sg0b * 8]);
            gload16(vr + (size_t)srowa * SEQ + sca, &VT[nb][sg0a * 8]);
            gload16(vr + (size_t)srowb * SEQ + scb, &VT[nb][sg0b * 8]);
        }

        const char* KHc = (const char*)KH[cur];
        const char* KLc = (const char*)KL[cur];
        const bool doA = (kt <= qtA);   // block-uniform
        uint2 paA[4], paB[4];
        float aloA[4], aloB[4];

        // ---- tile A: QK + softmax + pack (s dies before B's pass) ----
        if (doA) {
            f4v s[4] = {{0.f, 0.f, 0.f, 0.f}, {0.f, 0.f, 0.f, 0.f},
                        {0.f, 0.f, 0.f, 0.f}, {0.f, 0.f, 0.f, 0.f}};
#pragma unroll
            for (int ct = 0; ct < 4; ++ct) {
                int rr = ct * 16 + m, rb = rr * 128, sw = (rr & 7) << 4;
                s8v bh0 = *(const s8v*)(KHc + rb + ((g * 16) ^ sw));
                s8v bl0 = *(const s8v*)(KLc + rb + ((g * 16) ^ sw));
                s[ct] = MFMA(bh0, qA_h0, s[ct]);
                s[ct] = MFMA(bh0, qA_l0, s[ct]);
                s[ct] = MFMA(bl0, qA_h0, s[ct]);
                s8v bh1 = *(const s8v*)(KHc + rb + ((64 + g * 16) ^ sw));
                s8v bl1 = *(const s8v*)(KLc + rb + ((64 + g * 16) ^ sw));
                s[ct] = MFMA(bh1, qA_h1, s[ct]);
                s[ct] = MFMA(bh1, qA_l1, s[ct]);
                s[ct] = MFMA(bl1, qA_h1, s[ct]);
            }
            if (kt == qtA) {
#pragma unroll
                for (int ct = 0; ct < 4; ++ct)
#pragma unroll
                    for (int r = 0; r < 4; ++r)
                        if (ct * 16 + g * 4 + r > w * 16 + m) s[ct][r] = -1e30f;
            }
            float rm = -1e30f;
#pragma unroll
            for (int ct = 0; ct < 4; ++ct)
#pragma unroll
                for (int r = 0; r < 4; ++r) rm = fmaxf(rm, s[ct][r]);
            rm = fmaxf(rm, __shfl_xor(rm, 16, 64));
            rm = fmaxf(rm, __shfl_xor(rm, 32, 64));
            float mn = fmaxf(miA, rm);
            float al = __expf(miA - mn);
            miA = mn;
            float rs = 0.f;
#pragma unroll
            for (int ct = 0; ct < 4; ++ct)
#pragma unroll
                for (int r = 0; r < 4; ++r) {
                    s[ct][r] = __expf(s[ct][r] - mn);
                    rs += s[ct][r];
                }
            rs += __shfl_xor(rs, 16, 64);
            rs += __shfl_xor(rs, 32, 64);
            liA = liA * al + rs;
#pragma unroll
            for (int r = 0; r < 4; ++r) aloA[r] = __shfl(al, g * 4 + r, 64);
#pragma unroll
            for (int ct = 0; ct < 4; ++ct)
                paA[ct] = make_uint2(
                    (unsigned)f2bf(s[ct][0]) | ((unsigned)f2bf(s[ct][1]) << 16),
                    (unsigned)f2bf(s[ct][2]) | ((unsigned)f2bf(s[ct][3]) << 16));
        }

        // ---- tile B: QK + softmax + pack ----
        {
            f4v s[4] = {{0.f, 0.f, 0.f, 0.f}, {0.f, 0.f, 0.f, 0.f},
                        {0.f, 0.f, 0.f, 0.f}, {0.f, 0.f, 0.f, 0.f}};
#pragma unroll
            for (int ct = 0; ct < 4; ++ct) {
                int rr = ct * 16 + m, rb = rr * 128, sw = (rr & 7) << 4;
                s8v bh0 = *(const s8v*)(KHc + rb + ((g * 16) ^ sw));
                s8v bl0 = *(const s8v*)(KLc + rb + ((g * 16) ^ sw));
                s[ct] = MFMA(bh0, qB_h0, s[ct]);
                s[ct] = MFMA(bh0, qB_l0, s[ct]);
                s[ct] = MFMA(bl0, qB_h0, s[ct]);
                s8v bh1 = *(const s8v*)(KHc + rb + ((64 + g * 16) ^ sw));
                s8v bl1 = *(const s8v*)(KLc + rb + ((64 + g * 16) ^ sw));
                s[ct] = MFMA(bh1, qB_h1, s[ct]);
                s[ct] = MFMA(bh1, qB_l1, s[ct]);
                s[ct] = MFMA(bl1, qB_h1, s[ct]);
            }
            if (kt == qtB) {
#pragma unroll
                for (int ct = 0; ct < 4; ++ct)
#pragma unroll
                    for (int r = 0; r < 4; ++r)
                        if (ct * 16 + g * 4 + r > w * 16 + m) s[ct][r] = -1e30f;
            }
            float rm = -1e30f;
#pragma unroll
            for (int ct = 0; ct < 4; ++ct)
#pragma unroll
                for (int r = 0; r < 4; ++r) rm = fmaxf(rm, s[ct][r]);
            rm = fmaxf(rm, __shfl_xor(rm, 16, 64));
            rm = fmaxf(rm, __shfl_xor(rm, 32, 64));
            float mn = fmaxf(miB, rm);
            float al = __expf(miB - mn);
            miB = mn;
            float rs = 0.f;
#pragma unroll
            for (int ct = 0; ct < 4; ++ct)
#pragma unroll
                for (int r = 0; r < 4; ++r) {
                    s[ct][r] = __expf(s[ct][r] - mn);
                    rs += s[ct][r];
                }
            rs += __shfl_xor(rs, 16, 64);
            rs += __shfl_xor(rs, 32, 64);
            liB = liB * al + rs;
#pragma unroll
            for (int r = 0; r < 4; ++r) aloB[r] = __shfl(al, g * 4 + r, 64);
#pragma unroll
            for (int ct = 0; ct < 4; ++ct)
                paB[ct] = make_uint2(
                    (unsigned)f2bf(s[ct][0]) | ((unsigned)f2bf(s[ct][1]) << 16),
                    (unsigned)f2bf(s[ct][2]) | ((unsigned)f2bf(s[ct][3]) << 16));
        }

        __syncthreads();   // all waves done reading K[cur]; prefetch drains here

        const int pr = w * 16 + m, pb = pr * 128, psw = (pr & 7) << 4;
        if (doA) {   // P_A -> KH[cur] (dead); PV_A
#pragma unroll
            for (int ct = 0; ct < 4; ++ct)
                *(uint2*)((char*)KH[cur] + pb + ((ct * 32 + g * 8) ^ psw)) = paA[ct];
#pragma unroll
            for (int ct = 0; ct < 4; ++ct)
#pragma unroll
                for (int r = 0; r < 4; ++r) oA[ct][r] *= aloA[r];
#pragma unroll
            for (int kk = 0; kk < 2; ++kk) {
                s8v ap = *(const s8v*)((const char*)KH[cur] + pb + ((kk * 64 + g * 16) ^ psw));
#pragma unroll
                for (int ct = 0; ct < 4; ++ct) {
                    int vr2 = ct * 16 + m;
                    s8v bv = *(const s8v*)((const char*)VT[cur] + vr2 * 128 +
                                           ((kk * 64 + g * 16) ^ ((vr2 & 7) << 4)));
                    oA[ct] = MFMA(ap, bv, oA[ct]);
                }
            }
        }
        {   // P_B -> KL[cur] (dead); PV_B
#pragma unroll
            for (int ct = 0; ct < 4; ++ct)
                *(uint2*)((char*)KL[cur] + pb + ((ct * 32 + g * 8) ^ psw)) = paB[ct];
#pragma unroll
            for (int ct = 0; ct < 4; ++ct)
#pragma unroll
                for (int r = 0; r < 4; ++r) oB[ct][r] *= aloB[r];
#pragma unroll
            for (int kk = 0; kk < 2; ++kk) {
                s8v ap = *(const s8v*)((const char*)KL[cur] + pb + ((kk * 64 + g * 16) ^ psw));
#pragma unroll
                for (int ct = 0; ct < 4; ++ct) {
                    int vr2 = ct * 16 + m;
                    s8v bv = *(const s8v*)((const char*)VT[cur] + vr2 * 128 +
                                           ((kk * 64 + g * 16) ^ ((vr2 & 7) << 4)));
                    oB[ct] = MFMA(ap, bv, oB[ct]);
                }
            }
        }
        __syncthreads();   // PV done across waves -> buf[cur] recyclable next iter
        cur ^= 1;
    }

    // epilogue: two partials + two (m, l) rows
    const int TA = h * 160 + base16(qtA) + c;
    const int TB = h * 160 + base16(qtB) + c;
    float* poA = po_sel(TA, po_dout, po_wqt);
    float* poB = po_sel(TB, po_dout, po_wqt);
#pragma unroll
    for (int ct = 0; ct < 4; ++ct)
#pragma unroll
        for (int r = 0; r < 4; ++r) {
            poA[(size_t)(w * 16 + g * 4 + r) * 64 + ct * 16 + m] = oA[ct][r];
            poB[(size_t)(w * 16 + g * 4 + r) * 64 + ct * 16 + m] = oB[ct][r];
        }
    if (g == 0) {
        ml[(size_t)TA * 128 + w * 16 + m] = miA;
        ml[(size_t)TA * 128 + 64 + w * 16 + m] = liA;
        ml[(size_t)TB * 128 + w * 16 + m] = miB;
        ml[(size_t)TB * 128 + 64 + w * 16 + m] = liB;
    }
}

// ---------- merge split-KV partials -> atto bf16 ----------
__global__ __launch_bounds__(256) void attn_merge(
    float* __restrict__ po_dout, float* __restrict__ po_wqt,
    const float* __restrict__ ml, u16* __restrict__ atto) {
    const int qt = blockIdx.x, h = blockIdx.y;
    const int nc = (qt >> 4) + 1;
    const int t = threadIdx.x, col = t & 63, rg = t >> 6;
    const int T0 = h * 160 + base16(qt);
    for (int j = 0; j < 16; ++j) {
        int row = rg * 16 + j;
        float mv[4], lv[4], M = -1e30f;
#pragma unroll 4
        for (int cc = 0; cc < 4; ++cc)
            if (cc < nc) {
                mv[cc] = ml[(size_t)(T0 + cc) * 128 + row];
                lv[cc] = ml[(size_t)(T0 + cc) * 128 + 64 + row];
                M = fmaxf(M, mv[cc]);
            }
        float acc = 0.f, den = 0.f;
#pragma unroll 4
        for (int cc = 0; cc < 4; ++cc)
            if (cc < nc) {
                const float* po = po_sel(T0 + cc, po_dout, po_wqt);
                float wg = __expf(mv[cc] - M);
                den += lv[cc] * wg;
                acc += wg * po[(size_t)row * 64 + col];
            }
        atto[(size_t)(qt * 64 + row) * DINNER + h * 64 + col] = f2bf(acc / den);
    }
}

// ---------- fallback: original fused flash attention (used if workspace too small) ----------
__global__ __launch_bounds__(256) void attn_mfma(
    const u16* __restrict__ qh, const u16* __restrict__ ql,
    const u16* __restrict__ kh, const u16* __restrict__ kl,
    const u16* __restrict__ vt, u16* __restrict__ atto) {
    __shared__ u16 Qh[64 * PAD], Ql[64 * PAD], KP[64 * PAD], Kl[64 * PAD], Vt[64 * PAD];
    const int t = threadIdx.x;
    const int qt = blockIdx.x, h = blockIdx.y;
    const int w = t >> 6, lane = t & 63, m = lane & 15, q = lane >> 4;

#pragma unroll
    for (int i = 0; i < 2; ++i) {
        int c = t + i * 256, row = c >> 3, ch = (c & 7) * 8;
        *(uint4*)&Qh[row * PAD + ch] =
            *(const uint4*)&qh[(size_t)(qt * 64 + row) * DINNER + h * 64 + ch];
        *(uint4*)&Ql[row * PAD + ch] =
            *(const uint4*)&ql[(size_t)(qt * 64 + row) * DINNER + h * 64 + ch];
    }

    f4v o[4] = {{0.f, 0.f, 0.f, 0.f}, {0.f, 0.f, 0.f, 0.f},
                {0.f, 0.f, 0.f, 0.f}, {0.f, 0.f, 0.f, 0.f}};
    float mi[4] = {-1e30f, -1e30f, -1e30f, -1e30f};
    float li[4] = {0.f, 0.f, 0.f, 0.f};

    for (int kt = 0; kt <= qt; ++kt) {
        __syncthreads();
#pragma unroll
        for (int i = 0; i < 2; ++i) {
            int c = t + i * 256, row = c >> 3, ch = (c & 7) * 8;
            *(uint4*)&KP[row * PAD + ch] =
                *(const uint4*)&kh[(size_t)(kt * 64 + row) * DINNER + h * 64 + ch];
            *(uint4*)&Kl[row * PAD + ch] =
                *(const uint4*)&kl[(size_t)(kt * 64 + row) * DINNER + h * 64 + ch];
            *(uint4*)&Vt[row * PAD + ch] =
                *(const uint4*)&vt[(size_t)(h * 64 + row) * SEQ + kt * 64 + ch];
        }
        __syncthreads();

        f4v s[4] = {{0.f, 0.f, 0.f, 0.f}, {0.f, 0.f, 0.f, 0.f},
                    {0.f, 0.f, 0.f, 0.f}, {0.f, 0.f, 0.f, 0.f}};
#pragma unroll
        for (int kk = 0; kk < 64; kk += 32) {
            s8v ah = *(const s8v*)&Qh[(w * 16 + m) * PAD + kk + q * 8];
            s8v al = *(const s8v*)&Ql[(w * 16 + m) * PAD + kk + q * 8];
#pragma unroll
            for (int ct = 0; ct < 4; ++ct) {
                s8v bh = *(const s8v*)&KP[(ct * 16 + m) * PAD + kk + q * 8];
                s8v bl = *(const s8v*)&Kl[(ct * 16 + m) * PAD + kk + q * 8];
                s[ct] = MFMA(ah, bh, s[ct]);
                s[ct] = MFMA(al, bh, s[ct]);
                s[ct] = MFMA(ah, bl, s[ct]);
            }
        }
        if (kt == qt) {
#pragma unroll
            for (int ct = 0; ct < 4; ++ct)
#pragma unroll
                for (int r = 0; r < 4; ++r)
                    if (ct * 16 + m > w * 16 + q * 4 + r) s[ct][r] = -1e30f;
        }

        float alpha[4];
#pragma unroll
        for (int r = 0; r < 4; ++r) {
            float rm = fmaxf(fmaxf(s[0][r], s[1][r]), fmaxf(s[2][r], s[3][r]));
#pragma unroll
            for (int off = 8; off >= 1; off >>= 1) rm = fmaxf(rm, __shfl_xor(rm, off, 64));
            float mn = fmaxf(mi[r], rm);
            alpha[r] = __expf(mi[r] - mn);
            mi[r] = mn;
            float rs = 0.f;
#pragma unroll
            for (int ct = 0; ct < 4; ++ct) {
                s[ct][r] = __expf(s[ct][r] - mn);
                rs += s[ct][r];
            }
#pragma unroll
            for (int off = 8; off >= 1; off >>= 1) rs += __shfl_xor(rs, off, 64);
            li[r] = li[r] * alpha[r] + rs;
        }

        __syncthreads();
#pragma unroll
        for (int ct = 0; ct < 4; ++ct)
#pragma unroll
            for (int r = 0; r < 4; ++r) {
                KP[(w * 16 + q * 4 + r) * PAD + ct * 16 + m] = f2bf(s[ct][r]);
                o[ct][r] *= alpha[r];
            }
#pragma unroll
        for (int kk = 0; kk < 64; kk += 32) {
            s8v ap = *(const s8v*)&KP[(w * 16 + m) * PAD + kk + q * 8];
#pragma unroll
            for (int ct = 0; ct < 4; ++ct) {
                s8v bv = *(const s8v*)&Vt[(ct * 16 + m) * PAD + kk + q * 8];
                o[ct] = MFMA(ap, bv, o[ct]);
            }
        }
    }

#pragma unroll
    for (int r = 0; r < 4; ++r) {
        float inv = 1.0f / li[r];
#pragma unroll
        for (int ct = 0; ct < 4; ++ct)
            atto[(size_t)(qt * 64 + w * 16 + q * 4 + r) * DINNER + h * 64 + ct * 16 + m] =
                f2bf(o[ct][r] * inv);
    }
}

// ---------- out projection: 128x64 tile, global_load_lds + XOR swizzle ----------
__global__ __launch_bounds__(256) void gemm_out_128(const u16* __restrict__ A,
                                                    const u16* __restrict__ Bt,
                                                    float* __restrict__ C) {
    __shared__ __align__(16) u16 As[128 * 64], Bs[64 * 64];
    const int t = threadIdx.x;
    const int bn = blockIdx.x * 64, bm = blockIdx.y * 128;
    const int w = t >> 6, lane = t & 63, m = lane & 15, q = lane >> 4;
    const int wr = w >> 1, wc = w & 1;
    f4v acc[4][2];
#pragma unroll
    for (int i = 0; i < 4; ++i)
#pragma unroll
        for (int j = 0; j < 2; ++j) acc[i][j] = (f4v){0.f, 0.f, 0.f, 0.f};

    for (int k0 = 0; k0 < DINNER; k0 += 64) {
        __syncthreads();
#pragma unroll
        for (int i = 0; i < 4; ++i) {
            int idx0 = i * 256 + w * 64;
            int row = (idx0 + lane) >> 3;
            int col = ((lane & 7) * 8) ^ ((row & 7) * 8);
            gload16(&A[(size_t)(bm + row) * DINNER + k0 + col], &As[idx0 * 8]);
            if (i < 2)
                gload16(&Bt[(size_t)(bn + row) * DINNER + k0 + col], &Bs[idx0 * 8]);
        }
        __syncthreads();
#pragma unroll
        for (int kk = 0; kk < 64; kk += 32) {
            s8v a_f[4], b_f[2];
#pragma unroll
            for (int f = 0; f < 4; ++f) {
                int ar = wr * 64 + f * 16 + m;
                a_f[f] = *(const s8v*)((const char*)As + ar * 128 +
                                       (((kk + q * 8) * 2) ^ ((ar & 7) << 4)));
            }
#pragma unroll
            for (int f = 0; f < 2; ++f) {
                int br = wc * 32 + f * 16 + m;
                b_f[f] = *(const s8v*)((const char*)Bs + br * 128 +
                                       (((kk + q * 8) * 2) ^ ((br & 7) << 4)));
            }
#pragma unroll
            for (int fm = 0; fm < 4; ++fm)
#pragma unroll
                for (int fn = 0; fn < 2; ++fn)
                    acc[fm][fn] = MFMA(a_f[fm], b_f[fn], acc[fm][fn]);
        }
    }
#pragma unroll
    for (int fm = 0; fm < 4; ++fm)
#pragma unroll
        for (int fn = 0; fn < 2; ++fn)
#pragma unroll
            for (int r = 0; r < 4; ++r)
                C[(size_t)(bm + wr * 64 + fm * 16 + q * 4 + r) * DIM +
                  bn + wc * 32 + fn * 16 + m] = acc[fm][fn][r];
}

extern "C" void kernel_launch(void* const* d_in, const int* in_sizes, int n_in,
                              void* d_out, int out_size, void* d_ws, size_t ws_size,
                              hipStream_t stream) {
    const float* x     = (const float*)d_in[0];
    const float* gamma = (const float*)d_in[1];
    const float* w_qkv = (const float*)d_in[2];
    const float* w_out = (const float*)d_in[3];
    float* out = (float*)d_out;

    // normed hi/lo live in d_out (exact fit; consumed by gemm_qkv before partials overwrite)
    u16* nh = (u16*)d_out;
    u16* nl = nh + (size_t)SEQ * DIM;

    u16* p = (u16*)d_ws;
    u16* wqt_h = p; p += (size_t)QKVW * DIM;
    u16* wqt_l = p; p += (size_t)QKVW * DIM;
    u16* wot   = p; p += (size_t)DIM * DINNER;
    u16* qh = p; p += (size_t)SEQ * DINNER;
    u16* ql = p; p += (size_t)SEQ * DINNER;
    u16* kh = p; p += (size_t)SEQ * DINNER;
    u16* kl = p; p += (size_t)SEQ * DINNER;
    u16* vt = p; p += (size_t)DINNER * SEQ;
    u16* atto = p; p += (size_t)SEQ * DINNER;

    // split-KV partials: 1280 chunk-tiles x 16KB fp32. Tiles 0..1023 in d_out (16.78MB),
    // 1024..1279 in the dead wqt_h/wqt_l region. ml in ws.
    float* po_dout = (float*)d_out;
    float* po_wqt  = (float*)wqt_h;
    float* ml      = (float*)p;
    const size_t need = (size_t)((char*)(ml + (size_t)1280 * 128) - (char*)d_ws);  // ~32 MB
    const bool split = ws_size >= need;

    transpose_split<<<dim3(QKVW / 64, DIM / 64), 256, 0, stream>>>(w_qkv, wqt_h, wqt_l,
                                                                   DIM, QKVW, 1);
    transpose_split<<<dim3(DIM / 64, DINNER / 64), 256, 0, stream>>>(w_out, wot, nullptr,
                                                                     DINNER, DIM, 0);
    rmsnorm_split<<<SEQ, 256, 0, stream>>>(x, gamma, nh, nl);
    gemm_qkv_128<<<dim3(QKVW / 64, SEQ / 128), 256, 0, stream>>>(nh, nl, wqt_h, wqt_l,
                                                                 qh, ql, kh, kl, vt);
    if (split) {
        attn_chunk<<<dim3(128, HEADS), 256, 0, stream>>>(qh, ql, kh, kl, vt,
                                                         po_dout, po_wqt, ml);
        attn_merge<<<dim3(SEQ / 64, HEADS), 256, 0, stream>>>(po_dout, po_wqt, ml, atto);
    } else {
        attn_mfma<<<dim3(SEQ / 64, HEADS), 256, 0, stream>>>(qh, ql, kh, kl, vt, atto);
    }
    gemm_out_128<<<dim3(DIM / 64, SEQ / 128), 256, 0, stream>>>(atto, wot, out);
}